// Round 8
// baseline (3290.242 us; speedup 1.0000x reference)
//
#include <hip/hip_runtime.h>
#include <limits.h>

// ---------------- problem constants ----------------
constexpr int kB   = 128;   // batch
constexpr int kSin = 50;    // encoder seq len
constexpr int kT   = 25;    // decoder steps
constexpr int kD   = 128;   // feature dim
constexpr int kR   = 2048;  // RNN hidden
constexpr int kNB  = 256;   // grid blocks (1 per CU)
constexpr int kNT  = 512;   // threads per block (8 waves, 2/SIMD)
constexpr int kRing = 8;    // h ring depth (staleness window = 8 steps)

typedef __bf16 bf16x8 __attribute__((ext_vector_type(8)));
typedef float  f32x4  __attribute__((ext_vector_type(4)));
typedef unsigned short u16;
typedef unsigned long long u64;

__device__ __forceinline__ float bf2f(u16 u){ union{unsigned i; float f;}x; x.i=((unsigned)u)<<16; return x.f; }
__device__ __forceinline__ u16 f2bf(float f){ union{float f; unsigned i;}x; x.f=f; return (u16)((x.i + 0x7FFFu + ((x.i>>16)&1u))>>16); }
__device__ __forceinline__ float sigm(float x){ return 1.f/(1.f+__expf(-x)); }
__device__ __forceinline__ float tanhf_fast(float x){ return 1.f - 2.f/(__expf(2.f*x)+1.f); }

// ---- memory model (v11 = v10 + decoder algebraic fusion) ----
// Cross-block stores: relaxed agent atomics (write-through; MALL canonical).
// h reads: plain cached; 8-deep ring + acquire fence at GRU steps g%8==0.
// Flags: plain-store publication (r7), s_sleep(4) polls, rare RMW fallback.
// NEW: decoder phase B eliminated via v-recurrence (v=W_ih*x folded through
// fc2: v' = v + c + M*h, M = W_ih@fc2_w^T). Outputs reconstructed post-hoc
// from h-history (F-pass + prefix pass).
__device__ __forceinline__ void stg32(unsigned* p, unsigned v){
    __hip_atomic_store(p, v, __ATOMIC_RELAXED, __HIP_MEMORY_SCOPE_AGENT);
}
__device__ __forceinline__ void stg64(u64* p, u64 v){
    __hip_atomic_store(p, v, __ATOMIC_RELAXED, __HIP_MEMORY_SCOPE_AGENT);
}
__device__ __forceinline__ unsigned ald32(const void* p){
    return __hip_atomic_load((const unsigned*)p, __ATOMIC_RELAXED, __HIP_MEMORY_SCOPE_AGENT);
}
__device__ __forceinline__ float aldf(const float* p){
    union{ unsigned u; float f; } t; t.u = ald32(p); return t.f;
}

__device__ __forceinline__ bf16x8 pack8(float4 a, float4 b){
    union{ bf16x8 v; u16 u[8]; } t;
    t.u[0]=f2bf(a.x); t.u[1]=f2bf(a.y); t.u[2]=f2bf(a.z); t.u[3]=f2bf(a.w);
    t.u[4]=f2bf(b.x); t.u[5]=f2bf(b.y); t.u[6]=f2bf(b.z); t.u[7]=f2bf(b.w);
    return t.v;
}

// ---- fine-grained producer/consumer sync (r7 semantics) ----
__device__ __forceinline__ int pollflag(int* flags, int idx, int iter){
    if ((iter & 4095) == 4095) return atomicMax(&flags[idx*16], INT_MIN);
    return (int)ald32(&flags[idx*16]);
}
__device__ __forceinline__ void wait16(int* flags, int k, int base){
    const int lane = threadIdx.x & 63;
    for (int iter = 0;; ++iter){
        bool ok = true;
        if (lane < 16) ok = (pollflag(flags, base + lane, iter) >= k);
        if (__ballot(ok) == ~0ull) return;
        __builtin_amdgcn_s_sleep(4);
    }
}
__device__ __forceinline__ void gbar(int* flags, int k, int base, int perlane)
{
    __syncthreads();
    const int tid = threadIdx.x;
    if (tid == 0) atomicMax(&flags[blockIdx.x*16], k);
    if (tid < 64) {
        int iter = 0;
        for (;;) {
            bool ok = true;
            for (int j = 0; j < perlane; ++j) {
                const int idx = base + tid*perlane + j;
                int v;
                if ((iter & 511) == 511) v = atomicMax(&flags[idx*16], INT_MIN);
                else                     v = (int)ald32(&flags[idx*16]);
                ok &= (v >= k);
            }
            if (__ballot(ok) == ~0ull) break;
            ++iter;
            __builtin_amdgcn_s_sleep(2);
        }
    }
    __syncthreads();
}

__device__ __forceinline__ void cvt_f32_bf16(const float* __restrict__ s, u16* __restrict__ d,
                                             int n4, int gtid, int gstride)
{
    for (int i = gtid; i < n4; i += gstride) {
        float4 v = ((const float4*)s)[i];
        u64 pk = (u64)f2bf(v.x) | ((u64)f2bf(v.y)<<16) | ((u64)f2bf(v.z)<<32) | ((u64)f2bf(v.w)<<48);
        stg64((u64*)d + i, pk);
    }
}

// ---------------- single-iter GEMM (K=128) for fc1 (NT=8) ----------------
template<int NT, int NACC>
__device__ __forceinline__ void small_gemm(
    const u16* __restrict__ Am, int alda,
    const u16* __restrict__ Bp, int bldb,
    f32x4 (&acc)[NACC], u16* pool)
{
    const int tid=threadIdx.x, lane=tid&63, wv=tid>>6, g=wv>>2, mt=wv&3, ar=lane&15, aq=lane>>4;
    u16* sA = pool;
    u16* sB = pool + 8704;
    { int q=tid,     r=q>>4, c=q&15; *(uint4*)&sA[r*136+c*8] = *(const uint4*)(Am + r*alda + c*8); }
    { int q=tid+512, r=q>>4, c=q&15; *(uint4*)&sA[r*136+c*8] = *(const uint4*)(Am + r*alda + c*8); }
    for (int q=tid; q<NT*256; q+=kNT){
        int r=q>>4, c=q&15;
        *(uint4*)&sB[r*136+c*8] = *(const uint4*)(Bp + (size_t)r*bldb + c*8);
    }
    __syncthreads();
#pragma unroll
    for (int jt=0; jt<NT; ++jt){
        if ((jt&1) != g) continue;
#pragma unroll
        for (int kk=0; kk<4; ++kk){
            bf16x8 a = *(const bf16x8*)&sA[(mt*16+ar)*136 + kk*32 + aq*8];
            bf16x8 b = *(const bf16x8*)&sB[(jt*16+ar)*136 + kk*32 + aq*8];
            acc[jt>>1] = __builtin_amdgcn_mfma_f32_16x16x32_bf16(a,b,acc[jt>>1],0,0,0);
        }
    }
    __syncthreads();
}

// ---------------- ENCODER GRU step (r7, unchanged) ----------------
__device__ __forceinline__ void gru_phase_enc(
    const u16* __restrict__ hcur, u16* __restrict__ hnxt,
    const u16* __restrict__ xb,
    const bf16x8 (&wB)[3][8], const bf16x8 (&wI)[3],
    const float4 b4, float (&hprev)[4],
    int wgc, int mrow0, u16* smem,
    int* flags, int hk, int fbase, bool dofence, int setk)
{
    const int tid=threadIdx.x, lane=tid&63, w=tid>>6, ar=lane&15, aq=lane>>4;
    const f32x4 zz = {0.f,0.f,0.f,0.f};
    f32x4 acc[3][4] = {{zz,zz,zz,zz},{zz,zz,zz,zz},{zz,zz,zz,zz}};
    f32x4 xn[4] = {zz,zz,zz,zz};

    if (dofence) __builtin_amdgcn_fence(__ATOMIC_ACQUIRE, "agent");
    if (hk) wait16(flags, hk, fbase + 16*w);

#pragma unroll
    for (int mt=0; mt<4; ++mt){
        const int row = mrow0 + mt*16 + ar;
        bf16x8 af[8];
#pragma unroll
        for (int c=0; c<8; ++c){
            const int s = 16*w + 2*c + (aq>>1);
            af[c] = *(const bf16x8*)(hcur + (((s*128 + row)<<4) + (aq&1)*8));
        }
#pragma unroll
        for (int c=0; c<8; ++c){
            acc[0][mt] = __builtin_amdgcn_mfma_f32_16x16x32_bf16(af[c], wB[0][c], acc[0][mt],0,0,0);
            acc[1][mt] = __builtin_amdgcn_mfma_f32_16x16x32_bf16(af[c], wB[1][c], acc[1][mt],0,0,0);
            acc[2][mt] = __builtin_amdgcn_mfma_f32_16x16x32_bf16(af[c], wB[2][c], acc[2][mt],0,0,0);
        }
    }
    if (w < 4){
#pragma unroll
        for (int mt=0; mt<4; ++mt){
            bf16x8 ax = *(const bf16x8*)(xb + (mrow0+mt*16+ar)*kD + 32*w + aq*8);
            acc[0][mt] = __builtin_amdgcn_mfma_f32_16x16x32_bf16(ax, wI[0], acc[0][mt],0,0,0);
            acc[1][mt] = __builtin_amdgcn_mfma_f32_16x16x32_bf16(ax, wI[1], acc[1][mt],0,0,0);
            xn[mt]     = __builtin_amdgcn_mfma_f32_16x16x32_bf16(ax, wI[2], xn[mt],0,0,0);
        }
    }
    float* red = (float*)smem;
#define RCELL(wp,g4,mt) (red + (((((wp)*4+(g4))*4+(mt))*64 + lane)<<2))
    if (w >= 4){
#pragma unroll
        for (int g=0; g<3; ++g)
#pragma unroll
            for (int mt=0; mt<4; ++mt)
                *(f32x4*)RCELL(w-4, g, mt) = acc[g][mt];
    }
    __syncthreads();
    if (w < 4){
#pragma unroll
        for (int g=0; g<3; ++g)
#pragma unroll
            for (int mt=0; mt<4; ++mt)
                acc[g][mt] += *(f32x4*)RCELL(w, g, mt);
#pragma unroll
        for (int g=0; g<3; ++g)
#pragma unroll
            for (int mt=0; mt<4; ++mt)
                *(f32x4*)RCELL(w, g, mt) = acc[g][mt];
#pragma unroll
        for (int mt=0; mt<4; ++mt)
            *(f32x4*)RCELL(w, 3, mt) = xn[mt];
    }
    __syncthreads();
    if (tid < 256){
        const int mt = tid>>6, ls = tid&63, aqs = ls>>4, ars = ls&15;
        f32x4 R=zz, Z=zz, NH=zz, NX=zz;
#pragma unroll
        for (int wp=0; wp<4; ++wp){
            R  += *(f32x4*)(red + ((((wp*4+0)*4+mt)*64 + ls)<<2));
            Z  += *(f32x4*)(red + ((((wp*4+1)*4+mt)*64 + ls)<<2));
            NH += *(f32x4*)(red + ((((wp*4+2)*4+mt)*64 + ls)<<2));
            NX += *(f32x4*)(red + ((((wp*4+3)*4+mt)*64 + ls)<<2));
        }
#pragma unroll
        for (int rr=0; rr<4; ++rr){
            const int m = mrow0 + mt*16 + aqs*4 + rr;
            float r_ = sigm(R[rr] + b4.x);
            float z_ = sigm(Z[rr] + b4.y);
            float n_ = tanhf_fast(NX[rr] + b4.z + r_*(NH[rr] + b4.w));
            float hn = (1.f-z_)*n_ + z_*hprev[rr];
            hprev[rr] = hn;
            u16 hb = f2bf(hn);
            unsigned other = (unsigned)__shfl_xor((int)(unsigned)hb, 1);
            if (!(ars&1))
                stg32((unsigned*)(hnxt + ((wgc*128+m)<<4) + ars), (unsigned)hb | (other<<16));
        }
    }
#undef RCELL
    __syncthreads();
    if (setk && tid == 0) stg32((unsigned*)&flags[blockIdx.x*16], (unsigned)setk);
}

// ---------------- DECODER GRU step: W_hh*h and M*h, v-recurrence ----------------
// 6 reduce quantities (HHr,HHz,HHn,Mr,Mz,Mn): red = 4wp*6q*4mt*64*16B = 96 KB.
__device__ __forceinline__ void gru_phase_dec(
    const u16* __restrict__ hcur, u16* __restrict__ hnxt, u16* __restrict__ hist_d,
    const bf16x8 (&wB)[3][8], const bf16x8 (&wM)[3][8],
    const float4 b4, const float (&c3)[3], float (&v3)[3][4], float (&hprev)[4],
    int wgc, int mrow0, u16* smem,
    int* flags, int hk, int setk, int fbase, bool dofence, bool updv)
{
    const int tid=threadIdx.x, lane=tid&63, w=tid>>6, ar=lane&15, aq=lane>>4;
    const f32x4 zz = {0.f,0.f,0.f,0.f};
    f32x4 aH[3][4] = {{zz,zz,zz,zz},{zz,zz,zz,zz},{zz,zz,zz,zz}};
    f32x4 aM[3][4] = {{zz,zz,zz,zz},{zz,zz,zz,zz},{zz,zz,zz,zz}};

    if (dofence) __builtin_amdgcn_fence(__ATOMIC_ACQUIRE, "agent");
    if (hk) wait16(flags, hk, fbase + 16*w);

#pragma unroll
    for (int mt=0; mt<4; ++mt){
        const int row = mrow0 + mt*16 + ar;
        bf16x8 af[8];
#pragma unroll
        for (int c=0; c<8; ++c){
            const int s = 16*w + 2*c + (aq>>1);
            af[c] = *(const bf16x8*)(hcur + (((s*128 + row)<<4) + (aq&1)*8));
        }
#pragma unroll
        for (int c=0; c<8; ++c){
            aH[0][mt] = __builtin_amdgcn_mfma_f32_16x16x32_bf16(af[c], wB[0][c], aH[0][mt],0,0,0);
            aH[1][mt] = __builtin_amdgcn_mfma_f32_16x16x32_bf16(af[c], wB[1][c], aH[1][mt],0,0,0);
            aH[2][mt] = __builtin_amdgcn_mfma_f32_16x16x32_bf16(af[c], wB[2][c], aH[2][mt],0,0,0);
            aM[0][mt] = __builtin_amdgcn_mfma_f32_16x16x32_bf16(af[c], wM[0][c], aM[0][mt],0,0,0);
            aM[1][mt] = __builtin_amdgcn_mfma_f32_16x16x32_bf16(af[c], wM[1][c], aM[1][mt],0,0,0);
            aM[2][mt] = __builtin_amdgcn_mfma_f32_16x16x32_bf16(af[c], wM[2][c], aM[2][mt],0,0,0);
        }
    }
    float* red = (float*)smem;
#define RC6(wp,q,mt) (red + (((((wp)*6+(q))*4+(mt))*64 + lane)<<2))
    if (w >= 4){
#pragma unroll
        for (int g=0; g<3; ++g)
#pragma unroll
            for (int mt=0; mt<4; ++mt){
                *(f32x4*)RC6(w-4, g,   mt) = aH[g][mt];
                *(f32x4*)RC6(w-4, g+3, mt) = aM[g][mt];
            }
    }
    __syncthreads();
    if (w < 4){
#pragma unroll
        for (int g=0; g<3; ++g)
#pragma unroll
            for (int mt=0; mt<4; ++mt){
                aH[g][mt] += *(f32x4*)RC6(w, g,   mt);
                aM[g][mt] += *(f32x4*)RC6(w, g+3, mt);
                *(f32x4*)RC6(w, g,   mt) = aH[g][mt];
                *(f32x4*)RC6(w, g+3, mt) = aM[g][mt];
            }
    }
    __syncthreads();
    if (tid < 256){
        const int mt = tid>>6, ls = tid&63, aqs = ls>>4, ars = ls&15;
        f32x4 HR=zz, HZ=zz, HN=zz, MR=zz, MZ=zz, MN=zz;
#pragma unroll
        for (int wp=0; wp<4; ++wp){
            HR += *(f32x4*)(red + ((((wp*6+0)*4+mt)*64 + ls)<<2));
            HZ += *(f32x4*)(red + ((((wp*6+1)*4+mt)*64 + ls)<<2));
            HN += *(f32x4*)(red + ((((wp*6+2)*4+mt)*64 + ls)<<2));
            MR += *(f32x4*)(red + ((((wp*6+3)*4+mt)*64 + ls)<<2));
            MZ += *(f32x4*)(red + ((((wp*6+4)*4+mt)*64 + ls)<<2));
            MN += *(f32x4*)(red + ((((wp*6+5)*4+mt)*64 + ls)<<2));
        }
#pragma unroll
        for (int rr=0; rr<4; ++rr){
            if (updv){
                v3[0][rr] += c3[0] + MR[rr];
                v3[1][rr] += c3[1] + MZ[rr];
                v3[2][rr] += c3[2] + MN[rr];
            }
            const int m = mrow0 + mt*16 + aqs*4 + rr;
            float r_ = sigm(HR[rr] + v3[0][rr] + b4.x);
            float z_ = sigm(HZ[rr] + v3[1][rr] + b4.y);
            float n_ = tanhf_fast(v3[2][rr] + b4.z + r_*(HN[rr] + b4.w));
            float hn = (1.f-z_)*n_ + z_*hprev[rr];
            hprev[rr] = hn;
            u16 hb = f2bf(hn);
            unsigned other = (unsigned)__shfl_xor((int)(unsigned)hb, 1);
            if (!(ars&1)){
                stg32((unsigned*)(hnxt + ((wgc*128+m)<<4) + ars), (unsigned)hb | (other<<16));
                stg32((unsigned*)(hist_d + (size_t)m*kR + wgc*16 + ars), (unsigned)hb | (other<<16));
            }
        }
    }
#undef RC6
    __syncthreads();
    if (setk && tid == 0) stg32((unsigned*)&flags[blockIdx.x*16], (unsigned)setk);
}

// ---------------- the whole model, one persistent kernel ----------------
__global__ __launch_bounds__(kNT, 2) void seq2seq_kernel(
    const void* __restrict__ enc_in_raw, const void* __restrict__ fc1_w_raw,
    const void* __restrict__ fc1_b_raw,  const void* __restrict__ w_ih_raw,
    const void* __restrict__ w_hh_raw,   const void* __restrict__ b_ih_raw,
    const void* __restrict__ b_hh_raw,   const void* __restrict__ fc2_w_raw,
    const void* __restrict__ fc2_b_raw,
    void* __restrict__ out_raw,
    u16* __restrict__ enc_act,           // [50][128][128] bf16
    u16* __restrict__ h_b16,             // kRing x slice-major [128][128][16] bf16
    u16* __restrict__ hist,              // [25][128][2048] bf16 decoder h history
    float* __restrict__ Fbuf,            // [25][128][128] f32 fc2(h_d)
    u16* __restrict__ fc2T,              // [2048][128] bf16 fc2_w transposed
    float* __restrict__ encF,            // [128][128] f32
    float* __restrict__ bias,            // 6*kR + 2*kD f32
    int* flags,
    u16* __restrict__ cv_encx, u16* __restrict__ cv_fc1)
{
    __shared__ __align__(16) u16 smem[49152];   // 96 KB (dec 6-q reduce)
    __shared__ int sflag;
    const int wg = blockIdx.x, tid = threadIdx.x;
    const int wgc = wg & 127, mrow0 = (wg >> 7) * 64;
    const int lane = tid & 63, wv = tid >> 6, ar = lane & 15, aq = lane >> 4;
    const int gtid = wg * kNT + tid, gstride = kNB * kNT;
    const int dom = (wg >> 7) * 128;
    const size_t HS = (size_t)kB*kR;

    // ---- dtype detect ----
    {
        const u16* p = (const u16*)enc_in_raw;
        int found = 0;
        for (int i = tid; i < 16384; i += kNT) found |= ((p[i] & 0x7F80) == 0x7F80) ? 1 : 0;
        if (tid == 0) sflag = 0;
        __syncthreads();
        if (found) sflag = 1;
        __syncthreads();
    }
    const bool F32 = (sflag != 0);

    // ---- register-resident recurrent weights ----
    bf16x8 wB[3][8];
    bf16x8 wI[3];
    {
        const int w4 = wv & 3;
        if (F32){
            const float* Wh = (const float*)w_hh_raw;
            const float* Wi = (const float*)w_ih_raw;
#pragma unroll
            for (int g=0; g<3; ++g)
#pragma unroll
                for (int c=0; c<8; ++c){
                    size_t o = (size_t)(g*kR + wgc*16 + ar)*kR + 256*wv + 32*c + aq*8;
                    wB[g][c] = pack8(*(const float4*)(Wh+o), *(const float4*)(Wh+o+4));
                }
#pragma unroll
            for (int g=0; g<3; ++g){
                size_t o = (size_t)(g*kR + wgc*16 + ar)*kD + 32*w4 + aq*8;
                wI[g] = pack8(*(const float4*)(Wi+o), *(const float4*)(Wi+o+4));
            }
        } else {
            const u16* Wh = (const u16*)w_hh_raw;
            const u16* Wi = (const u16*)w_ih_raw;
#pragma unroll
            for (int g=0; g<3; ++g)
#pragma unroll
                for (int c=0; c<8; ++c)
                    wB[g][c] = *(const bf16x8*)(Wh + (size_t)(g*kR + wgc*16 + ar)*kR + 256*wv + 32*c + aq*8);
#pragma unroll
            for (int g=0; g<3; ++g)
                wI[g] = *(const bf16x8*)(Wi + (size_t)(g*kR + wgc*16 + ar)*kD + 32*w4 + aq*8);
        }
    }

    // ---- init: conversions + fc2T transpose + bias + zero h slot 0 ----
    if (F32) {
        cvt_f32_bf16((const float*)fc1_w_raw, cv_fc1,  (kD*kD)/4,       gtid, gstride);
        cvt_f32_bf16((const float*)enc_in_raw,cv_encx, (kB*kSin*kD)/4,  gtid, gstride);
        for (int i = gtid; i < 3*kR; i += gstride) {
            stg32((unsigned*)&bias[i],        __float_as_uint(((const float*)b_ih_raw)[i]));
            stg32((unsigned*)&bias[3*kR + i], __float_as_uint(((const float*)b_hh_raw)[i]));
        }
        for (int i = gtid; i < kD; i += gstride) {
            stg32((unsigned*)&bias[6*kR + i],      __float_as_uint(((const float*)fc1_b_raw)[i]));
            stg32((unsigned*)&bias[6*kR + kD + i], __float_as_uint(((const float*)fc2_b_raw)[i]));
        }
        const float* F2 = (const float*)fc2_w_raw;
        for (int i = gtid; i < (kR*kD)/2; i += gstride){   // u32 pairs of fc2T
            int k = i >> 6, jp = i & 63;
            unsigned lo = f2bf(F2[(size_t)(2*jp  )*kR + k]);
            unsigned hi = f2bf(F2[(size_t)(2*jp+1)*kR + k]);
            stg32((unsigned*)fc2T + (size_t)k*64 + jp, lo | (hi<<16));
        }
    } else {
        for (int i = gtid; i < 3*kR; i += gstride) {
            stg32((unsigned*)&bias[i],        __float_as_uint(bf2f(((const u16*)b_ih_raw)[i])));
            stg32((unsigned*)&bias[3*kR + i], __float_as_uint(bf2f(((const u16*)b_hh_raw)[i])));
        }
        for (int i = gtid; i < kD; i += gstride) {
            stg32((unsigned*)&bias[6*kR + i],      __float_as_uint(bf2f(((const u16*)fc1_b_raw)[i])));
            stg32((unsigned*)&bias[6*kR + kD + i], __float_as_uint(bf2f(((const u16*)fc2_b_raw)[i])));
        }
        const u16* F2 = (const u16*)fc2_w_raw;
        for (int i = gtid; i < (kR*kD)/2; i += gstride){
            int k = i >> 6, jp = i & 63;
            unsigned lo = F2[(size_t)(2*jp  )*kR + k];
            unsigned hi = F2[(size_t)(2*jp+1)*kR + k];
            stg32((unsigned*)fc2T + (size_t)k*64 + jp, lo | (hi<<16));
        }
    }
    for (int i = gtid; i < (int)((kB*kR)/2); i += gstride) stg32((unsigned*)h_b16 + i, 0u);
    gbar(flags, 1, 0, 4);                // tok 1: global barrier

    const u16* ENCX = F32 ? cv_encx : (const u16*)enc_in_raw;
    const u16* WF1  = F32 ? cv_fc1  : (const u16*)fc1_w_raw;

    // ---- wM: per-block M-slice = W_ih(48x128) @ fc2T(2048x128)^T, bf16 regs ----
    // wM[g][c] holds M[g*kR + wgc*16+ar][256*wv+32*c+aq*8 ..+8], same layout as wB.
    bf16x8 wM[3][8];
    {
#pragma unroll
        for (int g=0; g<3; ++g){
            const size_t wroff = (size_t)(g*kR + wgc*16 + ar)*kD;
#pragma unroll
            for (int c=0; c<8; ++c){
                const int kb = 256*wv + 32*c + aq*8;
                float a8[8] = {0.f,0.f,0.f,0.f,0.f,0.f,0.f,0.f};
                for (int j=0; j<kD; j+=8){
                    float wj[8];
                    if (F32){
                        const float* wr = (const float*)w_ih_raw + wroff + j;
#pragma unroll
                        for (int q2=0;q2<8;++q2) wj[q2] = wr[q2];
                    } else {
                        const u16* wr = (const u16*)w_ih_raw + wroff + j;
#pragma unroll
                        for (int q2=0;q2<8;++q2) wj[q2] = bf2f(wr[q2]);
                    }
#pragma unroll
                    for (int i=0;i<8;++i){
                        union{ bf16x8 v; u16 u[8]; } f8;
                        f8.v = *(const bf16x8*)(fc2T + (size_t)(kb+i)*kD + j);
#pragma unroll
                        for (int q2=0;q2<8;++q2) a8[i] += wj[q2] * bf2f(f8.u[q2]);
                    }
                }
                union{ bf16x8 v; u16 u[8]; } pk;
#pragma unroll
                for (int i=0;i<8;++i) pk.u[i] = f2bf(a8[i]);
                wM[g][c] = pk.v;
            }
        }
    }

    // ---- per-thread constants ----
    float4 b4;
    {
        const int hc = wgc*16 + ar;
        b4.x = aldf(&bias[hc])      + aldf(&bias[3*kR+hc]);
        b4.y = aldf(&bias[kR+hc])   + aldf(&bias[4*kR+hc]);
        b4.z = aldf(&bias[2*kR+hc]);
        b4.w = aldf(&bias[5*kR+hc]);
    }
    float hprev[4] = {0.f, 0.f, 0.f, 0.f};

    // ---- fc1 ----
    if (wgc < kSin) {
        const int g = wv>>2, mt = wv&3;
        const f32x4 zz = {0.f,0.f,0.f,0.f};
        f32x4 ae[4] = {zz,zz,zz,zz};
        small_gemm<8,4>(ENCX + ((size_t)mrow0*kSin + wgc)*kD, kSin*kD, WF1, kD, ae, smem);
#pragma unroll
        for (int jt=0; jt<8; ++jt){
            if ((jt&1) != g) continue;
            int col = jt*16 + ar;
            float fb = aldf(&bias[6*kR + col]);
#pragma unroll
            for (int rr=0; rr<4; ++rr){
                int m = mrow0 + mt*16 + aq*4 + rr;
                float v = ae[jt>>1][rr] + fb;
                u16 hb = f2bf(v);
                unsigned other = (unsigned)__shfl_xor((int)(unsigned)hb, 1);
                if (!(ar&1))
                    stg32((unsigned*)(enc_act + ((size_t)wgc*kB + m)*kD + col),
                          (unsigned)hb | (other<<16));
                if (wgc == kSin-1)
                    stg32((unsigned*)(encF + (size_t)m*kD + col), __float_as_uint(v));
            }
        }
    }
    gbar(flags, 2, dom, 2);              // tok 2: half-domain barrier

    // ---- encoder: 49 GRU steps; token H_t = t+3 ----
    for (int t = 0; t < kSin-1; ++t) {
        gru_phase_enc(h_b16 + (size_t)(t & 7)*HS, h_b16 + (size_t)((t+1) & 7)*HS,
                      enc_act + (size_t)t*kB*kD, wB, wI, b4, hprev, wgc, mrow0, smem,
                      flags, (t==0 ? 0 : t+2), dom, (t > 0) && ((t & 7) == 0), t+3);
    }

    // ---- decoder prologue: v0 = W_ih*encF, c3 = W_ih*fc2_b (f32) ----
    float v3[3][4] = {{0,0,0,0},{0,0,0,0},{0,0,0,0}};
    float c3[3] = {0.f,0.f,0.f};
    if (tid < 256){
        const int mtp = tid>>6, aqp = (tid&63)>>4, arp = tid&15;
        const int hc = wgc*16 + arp;
#pragma unroll
        for (int g=0; g<3; ++g){
            float cacc = 0.f, va0=0.f, va1=0.f, va2=0.f, va3=0.f;
            const int m0 = mrow0 + mtp*16 + aqp*4;
            if (F32){
                const float* wr = (const float*)w_ih_raw + (size_t)(g*kR + hc)*kD;
                for (int j=0;j<kD;++j){
                    float wj = wr[j];
                    cacc += wj * bias[6*kR + kD + j];
                    va0 += wj * encF[(size_t)(m0+0)*kD + j];
                    va1 += wj * encF[(size_t)(m0+1)*kD + j];
                    va2 += wj * encF[(size_t)(m0+2)*kD + j];
                    va3 += wj * encF[(size_t)(m0+3)*kD + j];
                }
            } else {
                const u16* wr = (const u16*)w_ih_raw + (size_t)(g*kR + hc)*kD;
                for (int j=0;j<kD;++j){
                    float wj = bf2f(wr[j]);
                    cacc += wj * bias[6*kR + kD + j];
                    va0 += wj * encF[(size_t)(m0+0)*kD + j];
                    va1 += wj * encF[(size_t)(m0+1)*kD + j];
                    va2 += wj * encF[(size_t)(m0+2)*kD + j];
                    va3 += wj * encF[(size_t)(m0+3)*kD + j];
                }
            }
            c3[g] = cacc;
            v3[g][0]=va0; v3[g][1]=va1; v3[g][2]=va2; v3[g][3]=va3;
        }
    }

    // ---- decoder: 25 uniform GRU steps; token = 52+d; only wait16 on h ----
    for (int d = 0; d < kT; ++d) {
        const int g = 49 + d;
        gru_phase_dec(h_b16 + (size_t)(g & 7)*HS, h_b16 + (size_t)((g+1) & 7)*HS,
                      hist + (size_t)d*kB*kR,
                      wB, wM, b4, c3, v3, hprev, wgc, mrow0, smem,
                      flags, 51+d, 52+d, dom, (g & 7) == 0, d > 0);
    }
    gbar(flags, 77, 0, 4);               // full barrier: all hist visible

    // ---- F-pass: F[e][m][j] = fc2(h_e)[m][j], grid-stride over 3200 units ----
    {
        float* sF = (float*)smem;
        const int j = tid & 127, kq = tid >> 7;
        for (int u = wg; u < kT*kB; u += kNB){
            const int e = u >> 7, m = u & 127;
            const u16* hb = hist + (size_t)(e*kB + m)*kR + kq*512;
            float p = 0.f;
            for (int kk=0; kk<512; kk+=8){
                union{ bf16x8 v; u16 u[8]; } hv;
                hv.v = *(const bf16x8*)(hb + kk);
#pragma unroll
                for (int i=0;i<8;++i){
                    u16 wv2 = fc2T[(size_t)(kq*512+kk+i)*kD + j];
                    p += bf2f(hv.u[i]) * bf2f(wv2);
                }
            }
            __syncthreads();
            sF[tid] = p;
            __syncthreads();
            if (tid < 128){
                float s = sF[tid] + sF[128+tid] + sF[256+tid] + sF[384+tid];
                stg32((unsigned*)&Fbuf[(size_t)(e*kB+m)*kD + tid], __float_as_uint(s));
            }
        }
    }
    gbar(flags, 78, 0, 4);               // full barrier: F visible

    // ---- prefix pass: out[m][e][j] = encF[m][j] + sum_{q<=e}(F_q + fc2_b) ----
    if (wg < 32){
        const int id = wg*kNT + tid;
        const int m = id >> 7, j = id & 127;
        float acc = encF[(size_t)m*kD + j];
        const float fb = bias[6*kR + kD + j];
        for (int e=0; e<kT; ++e){
            acc += Fbuf[(size_t)(e*kB + m)*kD + j] + fb;
            const size_t ob = ((size_t)m*kT + e)*kD + j;
            if (F32) ((float*)out_raw)[ob] = acc;
            else     ((u16*)out_raw)[ob]   = f2bf(acc);
        }
    }
}

// ---------------- host launcher ----------------
extern "C" void kernel_launch(void* const* d_in, const int* in_sizes, int n_in,
                              void* d_out, int out_size, void* d_ws, size_t ws_size,
                              hipStream_t stream)
{
    size_t off = 0;
    char* ws = (char*)d_ws;
    auto alloc = [&](size_t bytes) -> char* {
        char* p = ws + off;
        off = (off + bytes + 255) & ~(size_t)255;
        return p;
    };
    u16*   enc_act = (u16*)alloc((size_t)kSin*kB*kD*2);
    u16*   h_b16   = (u16*)alloc((size_t)kRing*kB*kR*2);         // 4 MB ring
    u16*   hist    = (u16*)alloc((size_t)kT*kB*kR*2);            // 12.8 MB
    float* Fbuf    = (float*)alloc((size_t)kT*kB*kD*4);          // 1.6 MB
    u16*   fc2T    = (u16*)alloc((size_t)kR*kD*2);               // 512 KB
    float* encF    = (float*)alloc((size_t)kB*kD*4);
    float* bias    = (float*)alloc((size_t)(6*kR + 2*kD)*4);
    int*   flags   = (int*)alloc((size_t)kNB*16*4);
    u16*   cv_encx = (u16*)alloc((size_t)kB*kSin*kD*2);
    u16*   cv_fc1  = (u16*)alloc((size_t)kD*kD*2);
    (void)ws_size; (void)in_sizes; (void)n_in; (void)out_size;

    seq2seq_kernel<<<dim3(kNB), dim3(kNT), 0, stream>>>(
        d_in[0], d_in[2], d_in[3], d_in[4], d_in[5], d_in[6], d_in[7], d_in[8], d_in[9],
        d_out,
        enc_act, h_b16, hist, Fbuf, fc2T, encF, bias, flags,
        cv_encx, cv_fc1);
}

// Round 9
// 2589.673 us; speedup vs baseline: 1.2705x; 1.2705x over previous
//
#include <hip/hip_runtime.h>
#include <limits.h>

// ---------------- problem constants ----------------
constexpr int kB   = 128;   // batch
constexpr int kSin = 50;    // encoder seq len
constexpr int kT   = 25;    // decoder steps
constexpr int kD   = 128;   // feature dim
constexpr int kR   = 2048;  // RNN hidden
constexpr int kNB  = 256;   // grid blocks (1 per CU)
constexpr int kNT  = 512;   // threads per block (8 waves, 2/SIMD)
constexpr int kRing = 8;    // h ring depth (staleness window = 8 steps)

typedef __bf16 bf16x8 __attribute__((ext_vector_type(8)));
typedef float  f32x4  __attribute__((ext_vector_type(4)));
typedef unsigned short u16;
typedef unsigned long long u64;

__device__ __forceinline__ float bf2f(u16 u){ union{unsigned i; float f;}x; x.i=((unsigned)u)<<16; return x.f; }
__device__ __forceinline__ u16 f2bf(float f){ union{float f; unsigned i;}x; x.f=f; return (u16)((x.i + 0x7FFFu + ((x.i>>16)&1u))>>16); }
__device__ __forceinline__ float sigm(float x){ return 1.f/(1.f+__expf(-x)); }
__device__ __forceinline__ float tanhf_fast(float x){ return 1.f - 2.f/(__expf(2.f*x)+1.f); }

// ---- memory model (v12 = v11 with MFMA-based init/F passes) ----
// Cross-block stores: relaxed agent atomics (write-through; MALL canonical).
// h reads: plain cached; 8-deep ring + acquire fence at GRU steps g%8==0.
// Flags: plain-store publication, s_sleep(4) polls, rare RMW fallback.
// Decoder: v-recurrence (v' = v + c + M*h, M = W_ih@fc2_w); outputs
// reconstructed post-hoc (MFMA F-pass + prefix pass). r8 verified the
// algebra (passed, absmax unchanged); r9 removes r8's 3.7 GB of scalar
// cache-thrash in the M-init and F-pass (measured FETCH 4.5 GB -> ~1 GB).
__device__ __forceinline__ void stg32(unsigned* p, unsigned v){
    __hip_atomic_store(p, v, __ATOMIC_RELAXED, __HIP_MEMORY_SCOPE_AGENT);
}
__device__ __forceinline__ void stg64(u64* p, u64 v){
    __hip_atomic_store(p, v, __ATOMIC_RELAXED, __HIP_MEMORY_SCOPE_AGENT);
}
__device__ __forceinline__ unsigned ald32(const void* p){
    return __hip_atomic_load((const unsigned*)p, __ATOMIC_RELAXED, __HIP_MEMORY_SCOPE_AGENT);
}
__device__ __forceinline__ float aldf(const float* p){
    union{ unsigned u; float f; } t; t.u = ald32(p); return t.f;
}

__device__ __forceinline__ bf16x8 pack8(float4 a, float4 b){
    union{ bf16x8 v; u16 u[8]; } t;
    t.u[0]=f2bf(a.x); t.u[1]=f2bf(a.y); t.u[2]=f2bf(a.z); t.u[3]=f2bf(a.w);
    t.u[4]=f2bf(b.x); t.u[5]=f2bf(b.y); t.u[6]=f2bf(b.z); t.u[7]=f2bf(b.w);
    return t.v;
}

// ---- fine-grained producer/consumer sync ----
__device__ __forceinline__ int pollflag(int* flags, int idx, int iter){
    if ((iter & 4095) == 4095) return atomicMax(&flags[idx*16], INT_MIN);
    return (int)ald32(&flags[idx*16]);
}
__device__ __forceinline__ void wait16(int* flags, int k, int base){
    const int lane = threadIdx.x & 63;
    for (int iter = 0;; ++iter){
        bool ok = true;
        if (lane < 16) ok = (pollflag(flags, base + lane, iter) >= k);
        if (__ballot(ok) == ~0ull) return;
        __builtin_amdgcn_s_sleep(4);
    }
}
__device__ __forceinline__ void gbar(int* flags, int k, int base, int perlane)
{
    __syncthreads();
    const int tid = threadIdx.x;
    if (tid == 0) atomicMax(&flags[blockIdx.x*16], k);
    if (tid < 64) {
        int iter = 0;
        for (;;) {
            bool ok = true;
            for (int j = 0; j < perlane; ++j) {
                const int idx = base + tid*perlane + j;
                int v;
                if ((iter & 511) == 511) v = atomicMax(&flags[idx*16], INT_MIN);
                else                     v = (int)ald32(&flags[idx*16]);
                ok &= (v >= k);
            }
            if (__ballot(ok) == ~0ull) break;
            ++iter;
            __builtin_amdgcn_s_sleep(2);
        }
    }
    __syncthreads();
}

__device__ __forceinline__ void cvt_f32_bf16(const float* __restrict__ s, u16* __restrict__ d,
                                             int n4, int gtid, int gstride)
{
    for (int i = gtid; i < n4; i += gstride) {
        float4 v = ((const float4*)s)[i];
        u64 pk = (u64)f2bf(v.x) | ((u64)f2bf(v.y)<<16) | ((u64)f2bf(v.z)<<32) | ((u64)f2bf(v.w)<<48);
        stg64((u64*)d + i, pk);
    }
}

// ---------------- single-iter GEMM (K=128) for fc1 (NT=8) ----------------
template<int NT, int NACC>
__device__ __forceinline__ void small_gemm(
    const u16* __restrict__ Am, int alda,
    const u16* __restrict__ Bp, int bldb,
    f32x4 (&acc)[NACC], u16* pool)
{
    const int tid=threadIdx.x, lane=tid&63, wv=tid>>6, g=wv>>2, mt=wv&3, ar=lane&15, aq=lane>>4;
    u16* sA = pool;
    u16* sB = pool + 8704;
    { int q=tid,     r=q>>4, c=q&15; *(uint4*)&sA[r*136+c*8] = *(const uint4*)(Am + r*alda + c*8); }
    { int q=tid+512, r=q>>4, c=q&15; *(uint4*)&sA[r*136+c*8] = *(const uint4*)(Am + r*alda + c*8); }
    for (int q=tid; q<NT*256; q+=kNT){
        int r=q>>4, c=q&15;
        *(uint4*)&sB[r*136+c*8] = *(const uint4*)(Bp + (size_t)r*bldb + c*8);
    }
    __syncthreads();
#pragma unroll
    for (int jt=0; jt<NT; ++jt){
        if ((jt&1) != g) continue;
#pragma unroll
        for (int kk=0; kk<4; ++kk){
            bf16x8 a = *(const bf16x8*)&sA[(mt*16+ar)*136 + kk*32 + aq*8];
            bf16x8 b = *(const bf16x8*)&sB[(jt*16+ar)*136 + kk*32 + aq*8];
            acc[jt>>1] = __builtin_amdgcn_mfma_f32_16x16x32_bf16(a,b,acc[jt>>1],0,0,0);
        }
    }
    __syncthreads();
}

// ---------------- ENCODER GRU step (r7, unchanged) ----------------
__device__ __forceinline__ void gru_phase_enc(
    const u16* __restrict__ hcur, u16* __restrict__ hnxt,
    const u16* __restrict__ xb,
    const bf16x8 (&wB)[3][8], const bf16x8 (&wI)[3],
    const float4 b4, float (&hprev)[4],
    int wgc, int mrow0, u16* smem,
    int* flags, int hk, int fbase, bool dofence, int setk)
{
    const int tid=threadIdx.x, lane=tid&63, w=tid>>6, ar=lane&15, aq=lane>>4;
    const f32x4 zz = {0.f,0.f,0.f,0.f};
    f32x4 acc[3][4] = {{zz,zz,zz,zz},{zz,zz,zz,zz},{zz,zz,zz,zz}};
    f32x4 xn[4] = {zz,zz,zz,zz};

    if (dofence) __builtin_amdgcn_fence(__ATOMIC_ACQUIRE, "agent");
    if (hk) wait16(flags, hk, fbase + 16*w);

#pragma unroll
    for (int mt=0; mt<4; ++mt){
        const int row = mrow0 + mt*16 + ar;
        bf16x8 af[8];
#pragma unroll
        for (int c=0; c<8; ++c){
            const int s = 16*w + 2*c + (aq>>1);
            af[c] = *(const bf16x8*)(hcur + (((s*128 + row)<<4) + (aq&1)*8));
        }
#pragma unroll
        for (int c=0; c<8; ++c){
            acc[0][mt] = __builtin_amdgcn_mfma_f32_16x16x32_bf16(af[c], wB[0][c], acc[0][mt],0,0,0);
            acc[1][mt] = __builtin_amdgcn_mfma_f32_16x16x32_bf16(af[c], wB[1][c], acc[1][mt],0,0,0);
            acc[2][mt] = __builtin_amdgcn_mfma_f32_16x16x32_bf16(af[c], wB[2][c], acc[2][mt],0,0,0);
        }
    }
    if (w < 4){
#pragma unroll
        for (int mt=0; mt<4; ++mt){
            bf16x8 ax = *(const bf16x8*)(xb + (mrow0+mt*16+ar)*kD + 32*w + aq*8);
            acc[0][mt] = __builtin_amdgcn_mfma_f32_16x16x32_bf16(ax, wI[0], acc[0][mt],0,0,0);
            acc[1][mt] = __builtin_amdgcn_mfma_f32_16x16x32_bf16(ax, wI[1], acc[1][mt],0,0,0);
            xn[mt]     = __builtin_amdgcn_mfma_f32_16x16x32_bf16(ax, wI[2], xn[mt],0,0,0);
        }
    }
    float* red = (float*)smem;
#define RCELL(wp,g4,mt) (red + (((((wp)*4+(g4))*4+(mt))*64 + lane)<<2))
    if (w >= 4){
#pragma unroll
        for (int g=0; g<3; ++g)
#pragma unroll
            for (int mt=0; mt<4; ++mt)
                *(f32x4*)RCELL(w-4, g, mt) = acc[g][mt];
    }
    __syncthreads();
    if (w < 4){
#pragma unroll
        for (int g=0; g<3; ++g)
#pragma unroll
            for (int mt=0; mt<4; ++mt)
                acc[g][mt] += *(f32x4*)RCELL(w, g, mt);
#pragma unroll
        for (int g=0; g<3; ++g)
#pragma unroll
            for (int mt=0; mt<4; ++mt)
                *(f32x4*)RCELL(w, g, mt) = acc[g][mt];
#pragma unroll
        for (int mt=0; mt<4; ++mt)
            *(f32x4*)RCELL(w, 3, mt) = xn[mt];
    }
    __syncthreads();
    if (tid < 256){
        const int mt = tid>>6, ls = tid&63, aqs = ls>>4, ars = ls&15;
        f32x4 R=zz, Z=zz, NH=zz, NX=zz;
#pragma unroll
        for (int wp=0; wp<4; ++wp){
            R  += *(f32x4*)(red + ((((wp*4+0)*4+mt)*64 + ls)<<2));
            Z  += *(f32x4*)(red + ((((wp*4+1)*4+mt)*64 + ls)<<2));
            NH += *(f32x4*)(red + ((((wp*4+2)*4+mt)*64 + ls)<<2));
            NX += *(f32x4*)(red + ((((wp*4+3)*4+mt)*64 + ls)<<2));
        }
#pragma unroll
        for (int rr=0; rr<4; ++rr){
            const int m = mrow0 + mt*16 + aqs*4 + rr;
            float r_ = sigm(R[rr] + b4.x);
            float z_ = sigm(Z[rr] + b4.y);
            float n_ = tanhf_fast(NX[rr] + b4.z + r_*(NH[rr] + b4.w));
            float hn = (1.f-z_)*n_ + z_*hprev[rr];
            hprev[rr] = hn;
            u16 hb = f2bf(hn);
            unsigned other = (unsigned)__shfl_xor((int)(unsigned)hb, 1);
            if (!(ars&1))
                stg32((unsigned*)(hnxt + ((wgc*128+m)<<4) + ars), (unsigned)hb | (other<<16));
        }
    }
#undef RCELL
    __syncthreads();
    if (setk && tid == 0) stg32((unsigned*)&flags[blockIdx.x*16], (unsigned)setk);
}

// ---------------- DECODER GRU step: W_hh*h and M*h, v-recurrence ----------------
__device__ __forceinline__ void gru_phase_dec(
    const u16* __restrict__ hcur, u16* __restrict__ hnxt, u16* __restrict__ hist_d,
    const bf16x8 (&wB)[3][8], const bf16x8 (&wM)[3][8],
    const float4 b4, const float (&c3)[3], float (&v3)[3][4], float (&hprev)[4],
    int wgc, int mrow0, u16* smem,
    int* flags, int hk, int setk, int fbase, bool dofence, bool updv)
{
    const int tid=threadIdx.x, lane=tid&63, w=tid>>6, ar=lane&15, aq=lane>>4;
    const f32x4 zz = {0.f,0.f,0.f,0.f};
    f32x4 aH[3][4] = {{zz,zz,zz,zz},{zz,zz,zz,zz},{zz,zz,zz,zz}};
    f32x4 aM[3][4] = {{zz,zz,zz,zz},{zz,zz,zz,zz},{zz,zz,zz,zz}};

    if (dofence) __builtin_amdgcn_fence(__ATOMIC_ACQUIRE, "agent");
    if (hk) wait16(flags, hk, fbase + 16*w);

#pragma unroll
    for (int mt=0; mt<4; ++mt){
        const int row = mrow0 + mt*16 + ar;
        bf16x8 af[8];
#pragma unroll
        for (int c=0; c<8; ++c){
            const int s = 16*w + 2*c + (aq>>1);
            af[c] = *(const bf16x8*)(hcur + (((s*128 + row)<<4) + (aq&1)*8));
        }
#pragma unroll
        for (int c=0; c<8; ++c){
            aH[0][mt] = __builtin_amdgcn_mfma_f32_16x16x32_bf16(af[c], wB[0][c], aH[0][mt],0,0,0);
            aH[1][mt] = __builtin_amdgcn_mfma_f32_16x16x32_bf16(af[c], wB[1][c], aH[1][mt],0,0,0);
            aH[2][mt] = __builtin_amdgcn_mfma_f32_16x16x32_bf16(af[c], wB[2][c], aH[2][mt],0,0,0);
            aM[0][mt] = __builtin_amdgcn_mfma_f32_16x16x32_bf16(af[c], wM[0][c], aM[0][mt],0,0,0);
            aM[1][mt] = __builtin_amdgcn_mfma_f32_16x16x32_bf16(af[c], wM[1][c], aM[1][mt],0,0,0);
            aM[2][mt] = __builtin_amdgcn_mfma_f32_16x16x32_bf16(af[c], wM[2][c], aM[2][mt],0,0,0);
        }
    }
    float* red = (float*)smem;
#define RC6(wp,q,mt) (red + (((((wp)*6+(q))*4+(mt))*64 + lane)<<2))
    if (w >= 4){
#pragma unroll
        for (int g=0; g<3; ++g)
#pragma unroll
            for (int mt=0; mt<4; ++mt){
                *(f32x4*)RC6(w-4, g,   mt) = aH[g][mt];
                *(f32x4*)RC6(w-4, g+3, mt) = aM[g][mt];
            }
    }
    __syncthreads();
    if (w < 4){
#pragma unroll
        for (int g=0; g<3; ++g)
#pragma unroll
            for (int mt=0; mt<4; ++mt){
                aH[g][mt] += *(f32x4*)RC6(w, g,   mt);
                aM[g][mt] += *(f32x4*)RC6(w, g+3, mt);
                *(f32x4*)RC6(w, g,   mt) = aH[g][mt];
                *(f32x4*)RC6(w, g+3, mt) = aM[g][mt];
            }
    }
    __syncthreads();
    if (tid < 256){
        const int mt = tid>>6, ls = tid&63, aqs = ls>>4, ars = ls&15;
        f32x4 HR=zz, HZ=zz, HN=zz, MR=zz, MZ=zz, MN=zz;
#pragma unroll
        for (int wp=0; wp<4; ++wp){
            HR += *(f32x4*)(red + ((((wp*6+0)*4+mt)*64 + ls)<<2));
            HZ += *(f32x4*)(red + ((((wp*6+1)*4+mt)*64 + ls)<<2));
            HN += *(f32x4*)(red + ((((wp*6+2)*4+mt)*64 + ls)<<2));
            MR += *(f32x4*)(red + ((((wp*6+3)*4+mt)*64 + ls)<<2));
            MZ += *(f32x4*)(red + ((((wp*6+4)*4+mt)*64 + ls)<<2));
            MN += *(f32x4*)(red + ((((wp*6+5)*4+mt)*64 + ls)<<2));
        }
#pragma unroll
        for (int rr=0; rr<4; ++rr){
            if (updv){
                v3[0][rr] += c3[0] + MR[rr];
                v3[1][rr] += c3[1] + MZ[rr];
                v3[2][rr] += c3[2] + MN[rr];
            }
            const int m = mrow0 + mt*16 + aqs*4 + rr;
            float r_ = sigm(HR[rr] + v3[0][rr] + b4.x);
            float z_ = sigm(HZ[rr] + v3[1][rr] + b4.y);
            float n_ = tanhf_fast(v3[2][rr] + b4.z + r_*(HN[rr] + b4.w));
            float hn = (1.f-z_)*n_ + z_*hprev[rr];
            hprev[rr] = hn;
            u16 hb = f2bf(hn);
            unsigned other = (unsigned)__shfl_xor((int)(unsigned)hb, 1);
            if (!(ars&1)){
                stg32((unsigned*)(hnxt + ((wgc*128+m)<<4) + ars), (unsigned)hb | (other<<16));
                stg32((unsigned*)(hist_d + (size_t)m*kR + wgc*16 + ars), (unsigned)hb | (other<<16));
            }
        }
    }
#undef RC6
    __syncthreads();
    if (setk && tid == 0) stg32((unsigned*)&flags[blockIdx.x*16], (unsigned)setk);
}

// ---------------- the whole model, one persistent kernel ----------------
__global__ __launch_bounds__(kNT, 2) void seq2seq_kernel(
    const void* __restrict__ enc_in_raw, const void* __restrict__ fc1_w_raw,
    const void* __restrict__ fc1_b_raw,  const void* __restrict__ w_ih_raw,
    const void* __restrict__ w_hh_raw,   const void* __restrict__ b_ih_raw,
    const void* __restrict__ b_hh_raw,   const void* __restrict__ fc2_w_raw,
    const void* __restrict__ fc2_b_raw,
    void* __restrict__ out_raw,
    u16* __restrict__ enc_act,           // [50][128][128] bf16
    u16* __restrict__ h_b16,             // kRing x slice-major [128][128][16] bf16
    u16* __restrict__ hist,              // [25][128][2048] bf16 decoder h history
    float* __restrict__ Fbuf,            // [25][128][128] f32 fc2(h_d)
    u16* __restrict__ fc2T,              // [2048][128] bf16 fc2_w transposed
    float* __restrict__ encF,            // [128][128] f32
    float* __restrict__ bias,            // 6*kR + 2*kD f32
    int* flags,
    u16* __restrict__ cv_encx, u16* __restrict__ cv_fc2, u16* __restrict__ cv_fc1)
{
    __shared__ __align__(16) u16 smem[49152];   // 96 KB (dec 6-q reduce)
    __shared__ int sflag;
    const int wg = blockIdx.x, tid = threadIdx.x;
    const int wgc = wg & 127, mrow0 = (wg >> 7) * 64;
    const int lane = tid & 63, wv = tid >> 6, ar = lane & 15, aq = lane >> 4;
    const int gtid = wg * kNT + tid, gstride = kNB * kNT;
    const int dom = (wg >> 7) * 128;
    const size_t HS = (size_t)kB*kR;

    // ---- dtype detect ----
    {
        const u16* p = (const u16*)enc_in_raw;
        int found = 0;
        for (int i = tid; i < 16384; i += kNT) found |= ((p[i] & 0x7F80) == 0x7F80) ? 1 : 0;
        if (tid == 0) sflag = 0;
        __syncthreads();
        if (found) sflag = 1;
        __syncthreads();
    }
    const bool F32 = (sflag != 0);

    // ---- register-resident recurrent weights ----
    bf16x8 wB[3][8];
    bf16x8 wI[3];
    {
        const int w4 = wv & 3;
        if (F32){
            const float* Wh = (const float*)w_hh_raw;
            const float* Wi = (const float*)w_ih_raw;
#pragma unroll
            for (int g=0; g<3; ++g)
#pragma unroll
                for (int c=0; c<8; ++c){
                    size_t o = (size_t)(g*kR + wgc*16 + ar)*kR + 256*wv + 32*c + aq*8;
                    wB[g][c] = pack8(*(const float4*)(Wh+o), *(const float4*)(Wh+o+4));
                }
#pragma unroll
            for (int g=0; g<3; ++g){
                size_t o = (size_t)(g*kR + wgc*16 + ar)*kD + 32*w4 + aq*8;
                wI[g] = pack8(*(const float4*)(Wi+o), *(const float4*)(Wi+o+4));
            }
        } else {
            const u16* Wh = (const u16*)w_hh_raw;
            const u16* Wi = (const u16*)w_ih_raw;
#pragma unroll
            for (int g=0; g<3; ++g)
#pragma unroll
                for (int c=0; c<8; ++c)
                    wB[g][c] = *(const bf16x8*)(Wh + (size_t)(g*kR + wgc*16 + ar)*kR + 256*wv + 32*c + aq*8);
#pragma unroll
            for (int g=0; g<3; ++g)
                wI[g] = *(const bf16x8*)(Wi + (size_t)(g*kR + wgc*16 + ar)*kD + 32*w4 + aq*8);
        }
    }

    // ---- init: conversions + fc2T transpose + bias + zero h slot 0 ----
    if (F32) {
        cvt_f32_bf16((const float*)fc1_w_raw, cv_fc1,  (kD*kD)/4,       gtid, gstride);
        cvt_f32_bf16((const float*)fc2_w_raw, cv_fc2,  (kD*kR)/4,       gtid, gstride);
        cvt_f32_bf16((const float*)enc_in_raw,cv_encx, (kB*kSin*kD)/4,  gtid, gstride);
        for (int i = gtid; i < 3*kR; i += gstride) {
            stg32((unsigned*)&bias[i],        __float_as_uint(((const float*)b_ih_raw)[i]));
            stg32((unsigned*)&bias[3*kR + i], __float_as_uint(((const float*)b_hh_raw)[i]));
        }
        for (int i = gtid; i < kD; i += gstride) {
            stg32((unsigned*)&bias[6*kR + i],      __float_as_uint(((const float*)fc1_b_raw)[i]));
            stg32((unsigned*)&bias[6*kR + kD + i], __float_as_uint(((const float*)fc2_b_raw)[i]));
        }
        const float* F2 = (const float*)fc2_w_raw;
        for (int i = gtid; i < (kR*kD)/2; i += gstride){
            int k = i >> 6, jp = i & 63;
            unsigned lo = f2bf(F2[(size_t)(2*jp  )*kR + k]);
            unsigned hi = f2bf(F2[(size_t)(2*jp+1)*kR + k]);
            stg32((unsigned*)fc2T + (size_t)k*64 + jp, lo | (hi<<16));
        }
    } else {
        for (int i = gtid; i < 3*kR; i += gstride) {
            stg32((unsigned*)&bias[i],        __float_as_uint(bf2f(((const u16*)b_ih_raw)[i])));
            stg32((unsigned*)&bias[3*kR + i], __float_as_uint(bf2f(((const u16*)b_hh_raw)[i])));
        }
        for (int i = gtid; i < kD; i += gstride) {
            stg32((unsigned*)&bias[6*kR + i],      __float_as_uint(bf2f(((const u16*)fc1_b_raw)[i])));
            stg32((unsigned*)&bias[6*kR + kD + i], __float_as_uint(bf2f(((const u16*)fc2_b_raw)[i])));
        }
        const u16* F2 = (const u16*)fc2_w_raw;
        for (int i = gtid; i < (kR*kD)/2; i += gstride){
            int k = i >> 6, jp = i & 63;
            unsigned lo = F2[(size_t)(2*jp  )*kR + k];
            unsigned hi = F2[(size_t)(2*jp+1)*kR + k];
            stg32((unsigned*)fc2T + (size_t)k*64 + jp, lo | (hi<<16));
        }
    }
    for (int i = gtid; i < (int)((kB*kR)/2); i += gstride) stg32((unsigned*)h_b16 + i, 0u);
    gbar(flags, 1, 0, 4);                // tok 1: global barrier

    const u16* ENCX = F32 ? cv_encx : (const u16*)enc_in_raw;
    const u16* WF1  = F32 ? cv_fc1  : (const u16*)fc1_w_raw;

    // ---- wM via MFMA, fully block-local (r8's scalar version was 6.4 GB of
    // cache-thrash). Stage W_ih 48x128 slice in LDS; B-frags straight from
    // fc2T (L2-hot); per gate route the 16x2048 result through a padded LDS
    // tile to convert MFMA C-layout -> wB-style fragment layout.
    bf16x8 wM[3][8];
    {
        u16* sA2 = smem;                 // 48 x 136  (13056 B)
        u16* sM  = smem + 6528;          // 16 x 2064 (66048 B); stride 2064 u16 = 4128 B (16B-mult, bank-spread)
        for (int q = tid; q < 48*16; q += kNT){
            int r = q >> 4, c = q & 15;
            int g = r >> 4, rr2 = r & 15;
            size_t off = (size_t)(g*kR + wgc*16 + rr2)*kD + c*8;
            bf16x8 v;
            if (F32) v = pack8(*(const float4*)((const float*)w_ih_raw + off),
                               *(const float4*)((const float*)w_ih_raw + off + 4));
            else     v = *(const bf16x8*)((const u16*)w_ih_raw + off);
            *(bf16x8*)&sA2[r*136 + c*8] = v;
        }
        __syncthreads();
        const f32x4 zzm = {0.f,0.f,0.f,0.f};
        for (int g=0; g<3; ++g){
            __syncthreads();             // prior gate's sM reads complete
            for (int jc=0; jc<4; ++jc){
                f32x4 acc[4] = {zzm,zzm,zzm,zzm};
#pragma unroll
                for (int jt=0; jt<4; ++jt){
                    const int cb = wv*256 + (jc*4+jt)*16;
#pragma unroll
                    for (int kk=0; kk<4; ++kk){
                        bf16x8 a = *(const bf16x8*)&sA2[(g*16+ar)*136 + kk*32 + aq*8];
                        bf16x8 b = *(const bf16x8*)(fc2T + (size_t)(cb + ar)*kD + kk*32 + aq*8);
                        acc[jt] = __builtin_amdgcn_mfma_f32_16x16x32_bf16(a, b, acc[jt],0,0,0);
                    }
                }
#pragma unroll
                for (int jt=0; jt<4; ++jt){
                    const int cb = wv*256 + (jc*4+jt)*16;
#pragma unroll
                    for (int rr2=0; rr2<4; ++rr2)
                        sM[(aq*4+rr2)*2064 + cb + ar] = f2bf(acc[jt][rr2]);
                }
            }
            __syncthreads();
#pragma unroll
            for (int c=0; c<8; ++c)
                wM[g][c] = *(const bf16x8*)&sM[ar*2064 + 256*wv + 32*c + aq*8];
        }
        __syncthreads();
    }

    // ---- per-thread constants ----
    float4 b4;
    {
        const int hc = wgc*16 + ar;
        b4.x = aldf(&bias[hc])      + aldf(&bias[3*kR+hc]);
        b4.y = aldf(&bias[kR+hc])   + aldf(&bias[4*kR+hc]);
        b4.z = aldf(&bias[2*kR+hc]);
        b4.w = aldf(&bias[5*kR+hc]);
    }
    float hprev[4] = {0.f, 0.f, 0.f, 0.f};

    // ---- fc1 ----
    if (wgc < kSin) {
        const int g = wv>>2, mt = wv&3;
        const f32x4 zz = {0.f,0.f,0.f,0.f};
        f32x4 ae[4] = {zz,zz,zz,zz};
        small_gemm<8,4>(ENCX + ((size_t)mrow0*kSin + wgc)*kD, kSin*kD, WF1, kD, ae, smem);
#pragma unroll
        for (int jt=0; jt<8; ++jt){
            if ((jt&1) != g) continue;
            int col = jt*16 + ar;
            float fb = aldf(&bias[6*kR + col]);
#pragma unroll
            for (int rr=0; rr<4; ++rr){
                int m = mrow0 + mt*16 + aq*4 + rr;
                float v = ae[jt>>1][rr] + fb;
                u16 hb = f2bf(v);
                unsigned other = (unsigned)__shfl_xor((int)(unsigned)hb, 1);
                if (!(ar&1))
                    stg32((unsigned*)(enc_act + ((size_t)wgc*kB + m)*kD + col),
                          (unsigned)hb | (other<<16));
                if (wgc == kSin-1)
                    stg32((unsigned*)(encF + (size_t)m*kD + col), __float_as_uint(v));
            }
        }
    }
    gbar(flags, 2, dom, 2);              // tok 2: half-domain barrier

    // ---- encoder: 49 GRU steps; token H_t = t+3 ----
    for (int t = 0; t < kSin-1; ++t) {
        gru_phase_enc(h_b16 + (size_t)(t & 7)*HS, h_b16 + (size_t)((t+1) & 7)*HS,
                      enc_act + (size_t)t*kB*kD, wB, wI, b4, hprev, wgc, mrow0, smem,
                      flags, (t==0 ? 0 : t+2), dom, (t > 0) && ((t & 7) == 0), t+3);
    }

    // ---- decoder prologue: v0 = W_ih*encF, c3 = W_ih*fc2_b (f32, L2-hot) ----
    float v3[3][4] = {{0,0,0,0},{0,0,0,0},{0,0,0,0}};
    float c3[3] = {0.f,0.f,0.f};
    if (tid < 256){
        const int mtp = tid>>6, aqp = (tid&63)>>4, arp = tid&15;
        const int hc = wgc*16 + arp;
#pragma unroll
        for (int g=0; g<3; ++g){
            float cacc = 0.f, va0=0.f, va1=0.f, va2=0.f, va3=0.f;
            const int m0 = mrow0 + mtp*16 + aqp*4;
            if (F32){
                const float* wr = (const float*)w_ih_raw + (size_t)(g*kR + hc)*kD;
                for (int j=0;j<kD;++j){
                    float wj = wr[j];
                    cacc += wj * bias[6*kR + kD + j];
                    va0 += wj * encF[(size_t)(m0+0)*kD + j];
                    va1 += wj * encF[(size_t)(m0+1)*kD + j];
                    va2 += wj * encF[(size_t)(m0+2)*kD + j];
                    va3 += wj * encF[(size_t)(m0+3)*kD + j];
                }
            } else {
                const u16* wr = (const u16*)w_ih_raw + (size_t)(g*kR + hc)*kD;
                for (int j=0;j<kD;++j){
                    float wj = bf2f(wr[j]);
                    cacc += wj * bias[6*kR + kD + j];
                    va0 += wj * encF[(size_t)(m0+0)*kD + j];
                    va1 += wj * encF[(size_t)(m0+1)*kD + j];
                    va2 += wj * encF[(size_t)(m0+2)*kD + j];
                    va3 += wj * encF[(size_t)(m0+3)*kD + j];
                }
            }
            c3[g] = cacc;
            v3[g][0]=va0; v3[g][1]=va1; v3[g][2]=va2; v3[g][3]=va3;
        }
    }

    // ---- decoder: 25 uniform GRU steps; token = 52+d; only wait16 on h ----
    for (int d = 0; d < kT; ++d) {
        const int g = 49 + d;
        gru_phase_dec(h_b16 + (size_t)(g & 7)*HS, h_b16 + (size_t)((g+1) & 7)*HS,
                      hist + (size_t)d*kB*kR,
                      wB, wM, b4, c3, v3, hprev, wgc, mrow0, smem,
                      flags, 51+d, 52+d, dom, (g & 7) == 0, d > 0);
    }
    gbar(flags, 77, 0, 4);               // full barrier: all hist visible

    // ---- F-pass via MFMA: F = hist(3200x2048) @ fc2_w^T(2048x128) ----
    {
        const u16* FC2W = F32 ? cv_fc2 : (const u16*)fc2_w_raw;
        for (int u = wg; u < (kT*kB)/16; u += kNB){
            const f32x4 zzf = {0.f,0.f,0.f,0.f};
            f32x4 acc = zzf;
            const u16* hb  = hist + (size_t)(u*16 + ar)*kR;
            const u16* wb2 = FC2W + (size_t)(wv*16 + ar)*kR;
            for (int kk=0; kk<64; ++kk){
                bf16x8 a = *(const bf16x8*)(hb + kk*32 + aq*8);
                bf16x8 b = *(const bf16x8*)(wb2 + kk*32 + aq*8);
                acc = __builtin_amdgcn_mfma_f32_16x16x32_bf16(a, b, acc,0,0,0);
            }
#pragma unroll
            for (int rr2=0; rr2<4; ++rr2)
                stg32((unsigned*)&Fbuf[(size_t)(u*16 + aq*4 + rr2)*kD + wv*16 + ar],
                      __float_as_uint(acc[rr2]));
        }
    }
    gbar(flags, 78, 0, 4);               // full barrier: F visible

    // ---- prefix pass: out[m][e][j] = encF[m][j] + sum_{q<=e}(F_q + fc2_b) ----
    if (wg < 32){
        const int id = wg*kNT + tid;
        const int m = id >> 7, j = id & 127;
        float acc = encF[(size_t)m*kD + j];
        const float fb = bias[6*kR + kD + j];
        for (int e=0; e<kT; ++e){
            acc += Fbuf[(size_t)(e*kB + m)*kD + j] + fb;
            const size_t ob = ((size_t)m*kT + e)*kD + j;
            if (F32) ((float*)out_raw)[ob] = acc;
            else     ((u16*)out_raw)[ob]   = f2bf(acc);
        }
    }
}

// ---------------- host launcher ----------------
extern "C" void kernel_launch(void* const* d_in, const int* in_sizes, int n_in,
                              void* d_out, int out_size, void* d_ws, size_t ws_size,
                              hipStream_t stream)
{
    size_t off = 0;
    char* ws = (char*)d_ws;
    auto alloc = [&](size_t bytes) -> char* {
        char* p = ws + off;
        off = (off + bytes + 255) & ~(size_t)255;
        return p;
    };
    u16*   enc_act = (u16*)alloc((size_t)kSin*kB*kD*2);
    u16*   h_b16   = (u16*)alloc((size_t)kRing*kB*kR*2);         // 4 MB ring
    u16*   hist    = (u16*)alloc((size_t)kT*kB*kR*2);            // 12.8 MB
    float* Fbuf    = (float*)alloc((size_t)kT*kB*kD*4);          // 1.6 MB
    u16*   fc2T    = (u16*)alloc((size_t)kR*kD*2);               // 512 KB
    float* encF    = (float*)alloc((size_t)kB*kD*4);
    float* bias    = (float*)alloc((size_t)(6*kR + 2*kD)*4);
    int*   flags   = (int*)alloc((size_t)kNB*16*4);
    u16*   cv_encx = (u16*)alloc((size_t)kB*kSin*kD*2);
    u16*   cv_fc2  = (u16*)alloc((size_t)kD*kR*2);
    u16*   cv_fc1  = (u16*)alloc((size_t)kD*kD*2);
    (void)ws_size; (void)in_sizes; (void)n_in; (void)out_size;

    seq2seq_kernel<<<dim3(kNB), dim3(kNT), 0, stream>>>(
        d_in[0], d_in[2], d_in[3], d_in[4], d_in[5], d_in[6], d_in[7], d_in[8], d_in[9],
        d_out,
        enc_act, h_b16, hist, Fbuf, fc2T, encF, bias, flags,
        cv_encx, cv_fc2, cv_fc1);
}

// Round 11
// 2403.348 us; speedup vs baseline: 1.3690x; 1.0775x over previous
//
#include <hip/hip_runtime.h>
#include <limits.h>

// ---------------- problem constants ----------------
constexpr int kB   = 128;   // batch
constexpr int kSin = 50;    // encoder seq len
constexpr int kT   = 25;    // decoder steps
constexpr int kD   = 128;   // feature dim
constexpr int kR   = 2048;  // RNN hidden
constexpr int kNB  = 256;   // grid blocks (1 per CU)
constexpr int kNT  = 512;   // threads per block (8 waves, 2/SIMD)
constexpr int kRing = 8;    // h ring depth (staleness window = 8 steps)

typedef __bf16 bf16x8 __attribute__((ext_vector_type(8)));
typedef float  f32x4  __attribute__((ext_vector_type(4)));
typedef unsigned short u16;
typedef unsigned long long u64;

__device__ __forceinline__ float bf2f(u16 u){ union{unsigned i; float f;}x; x.i=((unsigned)u)<<16; return x.f; }
__device__ __forceinline__ u16 f2bf(float f){ union{float f; unsigned i;}x; x.f=f; return (u16)((x.i + 0x7FFFu + ((x.i>>16)&1u))>>16); }
__device__ __forceinline__ float sigm(float x){ return 1.f/(1.f+__expf(-x)); }
__device__ __forceinline__ float tanhf_fast(float x){ return 1.f - 2.f/(__expf(2.f*x)+1.f); }

// ---- memory model (v13 = v12 with hist in packed slice-major layout) ----
// r9 post-mortem: hist stores were 4B-per-4KB-strided write-through -> one
// 4B store per 64B sector -> memory-side RMW (sector fetch + 16x write
// amplification) DRAINED BEFORE THE FLAG PUBLISH every decoder step
// (53 us/step vs encoder 14.3). hist now uses the h-ring's slice-major
// packed layout: identical store pattern as hnxt (64B lines fully covered).
__device__ __forceinline__ void stg32(unsigned* p, unsigned v){
    __hip_atomic_store(p, v, __ATOMIC_RELAXED, __HIP_MEMORY_SCOPE_AGENT);
}
__device__ __forceinline__ void stg64(u64* p, u64 v){
    __hip_atomic_store(p, v, __ATOMIC_RELAXED, __HIP_MEMORY_SCOPE_AGENT);
}
__device__ __forceinline__ unsigned ald32(const void* p){
    return __hip_atomic_load((const unsigned*)p, __ATOMIC_RELAXED, __HIP_MEMORY_SCOPE_AGENT);
}
__device__ __forceinline__ float aldf(const float* p){
    union{ unsigned u; float f; } t; t.u = ald32(p); return t.f;
}

__device__ __forceinline__ bf16x8 pack8(float4 a, float4 b){
    union{ bf16x8 v; u16 u[8]; } t;
    t.u[0]=f2bf(a.x); t.u[1]=f2bf(a.y); t.u[2]=f2bf(a.z); t.u[3]=f2bf(a.w);
    t.u[4]=f2bf(b.x); t.u[5]=f2bf(b.y); t.u[6]=f2bf(b.z); t.u[7]=f2bf(b.w);
    return t.v;
}

// ---- fine-grained producer/consumer sync ----
__device__ __forceinline__ int pollflag(int* flags, int idx, int iter){
    if ((iter & 4095) == 4095) return atomicMax(&flags[idx*16], INT_MIN);
    return (int)ald32(&flags[idx*16]);
}
__device__ __forceinline__ void wait16(int* flags, int k, int base){
    const int lane = threadIdx.x & 63;
    for (int iter = 0;; ++iter){
        bool ok = true;
        if (lane < 16) ok = (pollflag(flags, base + lane, iter) >= k);
        if (__ballot(ok) == ~0ull) return;
        __builtin_amdgcn_s_sleep(4);
    }
}
__device__ __forceinline__ void gbar(int* flags, int k, int base, int perlane)
{
    __syncthreads();
    const int tid = threadIdx.x;
    if (tid == 0) atomicMax(&flags[blockIdx.x*16], k);
    if (tid < 64) {
        int iter = 0;
        for (;;) {
            bool ok = true;
            for (int j = 0; j < perlane; ++j) {
                const int idx = base + tid*perlane + j;
                int v;
                if ((iter & 511) == 511) v = atomicMax(&flags[idx*16], INT_MIN);
                else                     v = (int)ald32(&flags[idx*16]);
                ok &= (v >= k);
            }
            if (__ballot(ok) == ~0ull) break;
            ++iter;
            __builtin_amdgcn_s_sleep(2);
        }
    }
    __syncthreads();
}

__device__ __forceinline__ void cvt_f32_bf16(const float* __restrict__ s, u16* __restrict__ d,
                                             int n4, int gtid, int gstride)
{
    for (int i = gtid; i < n4; i += gstride) {
        float4 v = ((const float4*)s)[i];
        u64 pk = (u64)f2bf(v.x) | ((u64)f2bf(v.y)<<16) | ((u64)f2bf(v.z)<<32) | ((u64)f2bf(v.w)<<48);
        stg64((u64*)d + i, pk);
    }
}

// ---------------- single-iter GEMM (K=128) for fc1 (NT=8) ----------------
template<int NT, int NACC>
__device__ __forceinline__ void small_gemm(
    const u16* __restrict__ Am, int alda,
    const u16* __restrict__ Bp, int bldb,
    f32x4 (&acc)[NACC], u16* pool)
{
    const int tid=threadIdx.x, lane=tid&63, wv=tid>>6, g=wv>>2, mt=wv&3, ar=lane&15, aq=lane>>4;
    u16* sA = pool;
    u16* sB = pool + 8704;
    { int q=tid,     r=q>>4, c=q&15; *(uint4*)&sA[r*136+c*8] = *(const uint4*)(Am + r*alda + c*8); }
    { int q=tid+512, r=q>>4, c=q&15; *(uint4*)&sA[r*136+c*8] = *(const uint4*)(Am + r*alda + c*8); }
    for (int q=tid; q<NT*256; q+=kNT){
        int r=q>>4, c=q&15;
        *(uint4*)&sB[r*136+c*8] = *(const uint4*)(Bp + (size_t)r*bldb + c*8);
    }
    __syncthreads();
#pragma unroll
    for (int jt=0; jt<NT; ++jt){
        if ((jt&1) != g) continue;
#pragma unroll
        for (int kk=0; kk<4; ++kk){
            bf16x8 a = *(const bf16x8*)&sA[(mt*16+ar)*136 + kk*32 + aq*8];
            bf16x8 b = *(const bf16x8*)&sB[(jt*16+ar)*136 + kk*32 + aq*8];
            acc[jt>>1] = __builtin_amdgcn_mfma_f32_16x16x32_bf16(a,b,acc[jt>>1],0,0,0);
        }
    }
    __syncthreads();
}

// ---------------- ENCODER GRU step (r7, unchanged) ----------------
__device__ __forceinline__ void gru_phase_enc(
    const u16* __restrict__ hcur, u16* __restrict__ hnxt,
    const u16* __restrict__ xb,
    const bf16x8 (&wB)[3][8], const bf16x8 (&wI)[3],
    const float4 b4, float (&hprev)[4],
    int wgc, int mrow0, u16* smem,
    int* flags, int hk, int fbase, bool dofence, int setk)
{
    const int tid=threadIdx.x, lane=tid&63, w=tid>>6, ar=lane&15, aq=lane>>4;
    const f32x4 zz = {0.f,0.f,0.f,0.f};
    f32x4 acc[3][4] = {{zz,zz,zz,zz},{zz,zz,zz,zz},{zz,zz,zz,zz}};
    f32x4 xn[4] = {zz,zz,zz,zz};

    if (dofence) __builtin_amdgcn_fence(__ATOMIC_ACQUIRE, "agent");
    if (hk) wait16(flags, hk, fbase + 16*w);

#pragma unroll
    for (int mt=0; mt<4; ++mt){
        const int row = mrow0 + mt*16 + ar;
        bf16x8 af[8];
#pragma unroll
        for (int c=0; c<8; ++c){
            const int s = 16*w + 2*c + (aq>>1);
            af[c] = *(const bf16x8*)(hcur + (((s*128 + row)<<4) + (aq&1)*8));
        }
#pragma unroll
        for (int c=0; c<8; ++c){
            acc[0][mt] = __builtin_amdgcn_mfma_f32_16x16x32_bf16(af[c], wB[0][c], acc[0][mt],0,0,0);
            acc[1][mt] = __builtin_amdgcn_mfma_f32_16x16x32_bf16(af[c], wB[1][c], acc[1][mt],0,0,0);
            acc[2][mt] = __builtin_amdgcn_mfma_f32_16x16x32_bf16(af[c], wB[2][c], acc[2][mt],0,0,0);
        }
    }
    if (w < 4){
#pragma unroll
        for (int mt=0; mt<4; ++mt){
            bf16x8 ax = *(const bf16x8*)(xb + (mrow0+mt*16+ar)*kD + 32*w + aq*8);
            acc[0][mt] = __builtin_amdgcn_mfma_f32_16x16x32_bf16(ax, wI[0], acc[0][mt],0,0,0);
            acc[1][mt] = __builtin_amdgcn_mfma_f32_16x16x32_bf16(ax, wI[1], acc[1][mt],0,0,0);
            xn[mt]     = __builtin_amdgcn_mfma_f32_16x16x32_bf16(ax, wI[2], xn[mt],0,0,0);
        }
    }
    float* red = (float*)smem;
#define RCELL(wp,g4,mt) (red + (((((wp)*4+(g4))*4+(mt))*64 + lane)<<2))
    if (w >= 4){
#pragma unroll
        for (int g=0; g<3; ++g)
#pragma unroll
            for (int mt=0; mt<4; ++mt)
                *(f32x4*)RCELL(w-4, g, mt) = acc[g][mt];
    }
    __syncthreads();
    if (w < 4){
#pragma unroll
        for (int g=0; g<3; ++g)
#pragma unroll
            for (int mt=0; mt<4; ++mt)
                acc[g][mt] += *(f32x4*)RCELL(w, g, mt);
#pragma unroll
        for (int g=0; g<3; ++g)
#pragma unroll
            for (int mt=0; mt<4; ++mt)
                *(f32x4*)RCELL(w, g, mt) = acc[g][mt];
#pragma unroll
        for (int mt=0; mt<4; ++mt)
            *(f32x4*)RCELL(w, 3, mt) = xn[mt];
    }
    __syncthreads();
    if (tid < 256){
        const int mt = tid>>6, ls = tid&63, aqs = ls>>4, ars = ls&15;
        f32x4 R=zz, Z=zz, NH=zz, NX=zz;
#pragma unroll
        for (int wp=0; wp<4; ++wp){
            R  += *(f32x4*)(red + ((((wp*4+0)*4+mt)*64 + ls)<<2));
            Z  += *(f32x4*)(red + ((((wp*4+1)*4+mt)*64 + ls)<<2));
            NH += *(f32x4*)(red + ((((wp*4+2)*4+mt)*64 + ls)<<2));
            NX += *(f32x4*)(red + ((((wp*4+3)*4+mt)*64 + ls)<<2));
        }
#pragma unroll
        for (int rr=0; rr<4; ++rr){
            const int m = mrow0 + mt*16 + aqs*4 + rr;
            float r_ = sigm(R[rr] + b4.x);
            float z_ = sigm(Z[rr] + b4.y);
            float n_ = tanhf_fast(NX[rr] + b4.z + r_*(NH[rr] + b4.w));
            float hn = (1.f-z_)*n_ + z_*hprev[rr];
            hprev[rr] = hn;
            u16 hb = f2bf(hn);
            unsigned other = (unsigned)__shfl_xor((int)(unsigned)hb, 1);
            if (!(ars&1))
                stg32((unsigned*)(hnxt + ((wgc*128+m)<<4) + ars), (unsigned)hb | (other<<16));
        }
    }
#undef RCELL
    __syncthreads();
    if (setk && tid == 0) stg32((unsigned*)&flags[blockIdx.x*16], (unsigned)setk);
}

// ---------------- DECODER GRU step: W_hh*h and M*h, v-recurrence ----------------
// hist_d is SLICE-MAJOR (same layout/store pattern as the h ring): packed
// u32 stores fully covering 64B lines -> no memory-side RMW in the drain.
__device__ __forceinline__ void gru_phase_dec(
    const u16* __restrict__ hcur, u16* __restrict__ hnxt, u16* __restrict__ hist_d,
    const bf16x8 (&wB)[3][8], const bf16x8 (&wM)[3][8],
    const float4 b4, const float (&c3)[3], float (&v3)[3][4], float (&hprev)[4],
    int wgc, int mrow0, u16* smem,
    int* flags, int hk, int setk, int fbase, bool dofence, bool updv)
{
    const int tid=threadIdx.x, lane=tid&63, w=tid>>6, ar=lane&15, aq=lane>>4;
    const f32x4 zz = {0.f,0.f,0.f,0.f};
    f32x4 aH[3][4] = {{zz,zz,zz,zz},{zz,zz,zz,zz},{zz,zz,zz,zz}};
    f32x4 aM[3][4] = {{zz,zz,zz,zz},{zz,zz,zz,zz},{zz,zz,zz,zz}};

    if (dofence) __builtin_amdgcn_fence(__ATOMIC_ACQUIRE, "agent");
    if (hk) wait16(flags, hk, fbase + 16*w);

#pragma unroll
    for (int mt=0; mt<4; ++mt){
        const int row = mrow0 + mt*16 + ar;
        bf16x8 af[8];
#pragma unroll
        for (int c=0; c<8; ++c){
            const int s = 16*w + 2*c + (aq>>1);
            af[c] = *(const bf16x8*)(hcur + (((s*128 + row)<<4) + (aq&1)*8));
        }
#pragma unroll
        for (int c=0; c<8; ++c){
            aH[0][mt] = __builtin_amdgcn_mfma_f32_16x16x32_bf16(af[c], wB[0][c], aH[0][mt],0,0,0);
            aH[1][mt] = __builtin_amdgcn_mfma_f32_16x16x32_bf16(af[c], wB[1][c], aH[1][mt],0,0,0);
            aH[2][mt] = __builtin_amdgcn_mfma_f32_16x16x32_bf16(af[c], wB[2][c], aH[2][mt],0,0,0);
            aM[0][mt] = __builtin_amdgcn_mfma_f32_16x16x32_bf16(af[c], wM[0][c], aM[0][mt],0,0,0);
            aM[1][mt] = __builtin_amdgcn_mfma_f32_16x16x32_bf16(af[c], wM[1][c], aM[1][mt],0,0,0);
            aM[2][mt] = __builtin_amdgcn_mfma_f32_16x16x32_bf16(af[c], wM[2][c], aM[2][mt],0,0,0);
        }
    }
    float* red = (float*)smem;
#define RC6(wp,q,mt) (red + (((((wp)*6+(q))*4+(mt))*64 + lane)<<2))
    if (w >= 4){
#pragma unroll
        for (int g=0; g<3; ++g)
#pragma unroll
            for (int mt=0; mt<4; ++mt){
                *(f32x4*)RC6(w-4, g,   mt) = aH[g][mt];
                *(f32x4*)RC6(w-4, g+3, mt) = aM[g][mt];
            }
    }
    __syncthreads();
    if (w < 4){
#pragma unroll
        for (int g=0; g<3; ++g)
#pragma unroll
            for (int mt=0; mt<4; ++mt){
                aH[g][mt] += *(f32x4*)RC6(w, g,   mt);
                aM[g][mt] += *(f32x4*)RC6(w, g+3, mt);
                *(f32x4*)RC6(w, g,   mt) = aH[g][mt];
                *(f32x4*)RC6(w, g+3, mt) = aM[g][mt];
            }
    }
    __syncthreads();
    if (tid < 256){
        const int mt = tid>>6, ls = tid&63, aqs = ls>>4, ars = ls&15;
        f32x4 HR=zz, HZ=zz, HN=zz, MR=zz, MZ=zz, MN=zz;
#pragma unroll
        for (int wp=0; wp<4; ++wp){
            HR += *(f32x4*)(red + ((((wp*6+0)*4+mt)*64 + ls)<<2));
            HZ += *(f32x4*)(red + ((((wp*6+1)*4+mt)*64 + ls)<<2));
            HN += *(f32x4*)(red + ((((wp*6+2)*4+mt)*64 + ls)<<2));
            MR += *(f32x4*)(red + ((((wp*6+3)*4+mt)*64 + ls)<<2));
            MZ += *(f32x4*)(red + ((((wp*6+4)*4+mt)*64 + ls)<<2));
            MN += *(f32x4*)(red + ((((wp*6+5)*4+mt)*64 + ls)<<2));
        }
#pragma unroll
        for (int rr=0; rr<4; ++rr){
            if (updv){
                v3[0][rr] += c3[0] + MR[rr];
                v3[1][rr] += c3[1] + MZ[rr];
                v3[2][rr] += c3[2] + MN[rr];
            }
            const int m = mrow0 + mt*16 + aqs*4 + rr;
            float r_ = sigm(HR[rr] + v3[0][rr] + b4.x);
            float z_ = sigm(HZ[rr] + v3[1][rr] + b4.y);
            float n_ = tanhf_fast(v3[2][rr] + b4.z + r_*(HN[rr] + b4.w));
            float hn = (1.f-z_)*n_ + z_*hprev[rr];
            hprev[rr] = hn;
            u16 hb = f2bf(hn);
            unsigned other = (unsigned)__shfl_xor((int)(unsigned)hb, 1);
            if (!(ars&1)){
                unsigned pk2 = (unsigned)hb | (other<<16);
                stg32((unsigned*)(hnxt   + ((wgc*128+m)<<4) + ars), pk2);
                stg32((unsigned*)(hist_d + ((wgc*128+m)<<4) + ars), pk2);
            }
        }
    }
#undef RC6
    __syncthreads();
    if (setk && tid == 0) stg32((unsigned*)&flags[blockIdx.x*16], (unsigned)setk);
}

// ---------------- the whole model, one persistent kernel ----------------
__global__ __launch_bounds__(kNT, 2) void seq2seq_kernel(
    const void* __restrict__ enc_in_raw, const void* __restrict__ fc1_w_raw,
    const void* __restrict__ fc1_b_raw,  const void* __restrict__ w_ih_raw,
    const void* __restrict__ w_hh_raw,   const void* __restrict__ b_ih_raw,
    const void* __restrict__ b_hh_raw,   const void* __restrict__ fc2_w_raw,
    const void* __restrict__ fc2_b_raw,
    void* __restrict__ out_raw,
    u16* __restrict__ enc_act,           // [50][128][128] bf16
    u16* __restrict__ h_b16,             // kRing x slice-major [128][128][16] bf16
    u16* __restrict__ hist,              // [25] x slice-major [128][128][16] bf16
    float* __restrict__ Fbuf,            // [25][128][128] f32 fc2(h_d)
    u16* __restrict__ fc2T,              // [2048][128] bf16 fc2_w transposed
    float* __restrict__ encF,            // [128][128] f32
    float* __restrict__ bias,            // 6*kR + 2*kD f32
    int* flags,
    u16* __restrict__ cv_encx, u16* __restrict__ cv_fc2, u16* __restrict__ cv_fc1)
{
    __shared__ __align__(16) u16 smem[49152];   // 96 KB (dec 6-q reduce)
    __shared__ int sflag;
    const int wg = blockIdx.x, tid = threadIdx.x;
    const int wgc = wg & 127, mrow0 = (wg >> 7) * 64;
    const int lane = tid & 63, wv = tid >> 6, ar = lane & 15, aq = lane >> 4;
    const int gtid = wg * kNT + tid, gstride = kNB * kNT;
    const int dom = (wg >> 7) * 128;
    const size_t HS = (size_t)kB*kR;

    // ---- dtype detect ----
    {
        const u16* p = (const u16*)enc_in_raw;
        int found = 0;
        for (int i = tid; i < 16384; i += kNT) found |= ((p[i] & 0x7F80) == 0x7F80) ? 1 : 0;
        if (tid == 0) sflag = 0;
        __syncthreads();
        if (found) sflag = 1;
        __syncthreads();
    }
    const bool F32 = (sflag != 0);

    // ---- register-resident recurrent weights ----
    bf16x8 wB[3][8];
    bf16x8 wI[3];
    {
        const int w4 = wv & 3;
        if (F32){
            const float* Wh = (const float*)w_hh_raw;
            const float* Wi = (const float*)w_ih_raw;
#pragma unroll
            for (int g=0; g<3; ++g)
#pragma unroll
                for (int c=0; c<8; ++c){
                    size_t o = (size_t)(g*kR + wgc*16 + ar)*kR + 256*wv + 32*c + aq*8;
                    wB[g][c] = pack8(*(const float4*)(Wh+o), *(const float4*)(Wh+o+4));
                }
#pragma unroll
            for (int g=0; g<3; ++g){
                size_t o = (size_t)(g*kR + wgc*16 + ar)*kD + 32*w4 + aq*8;
                wI[g] = pack8(*(const float4*)(Wi+o), *(const float4*)(Wi+o+4));
            }
        } else {
            const u16* Wh = (const u16*)w_hh_raw;
            const u16* Wi = (const u16*)w_ih_raw;
#pragma unroll
            for (int g=0; g<3; ++g)
#pragma unroll
                for (int c=0; c<8; ++c)
                    wB[g][c] = *(const bf16x8*)(Wh + (size_t)(g*kR + wgc*16 + ar)*kR + 256*wv + 32*c + aq*8);
#pragma unroll
            for (int g=0; g<3; ++g)
                wI[g] = *(const bf16x8*)(Wi + (size_t)(g*kR + wgc*16 + ar)*kD + 32*w4 + aq*8);
        }
    }

    // ---- init: conversions + fc2T transpose + bias + zero h slot 0 ----
    if (F32) {
        cvt_f32_bf16((const float*)fc1_w_raw, cv_fc1,  (kD*kD)/4,       gtid, gstride);
        cvt_f32_bf16((const float*)fc2_w_raw, cv_fc2,  (kD*kR)/4,       gtid, gstride);
        cvt_f32_bf16((const float*)enc_in_raw,cv_encx, (kB*kSin*kD)/4,  gtid, gstride);
        for (int i = gtid; i < 3*kR; i += gstride) {
            stg32((unsigned*)&bias[i],        __float_as_uint(((const float*)b_ih_raw)[i]));
            stg32((unsigned*)&bias[3*kR + i], __float_as_uint(((const float*)b_hh_raw)[i]));
        }
        for (int i = gtid; i < kD; i += gstride) {
            stg32((unsigned*)&bias[6*kR + i],      __float_as_uint(((const float*)fc1_b_raw)[i]));
            stg32((unsigned*)&bias[6*kR + kD + i], __float_as_uint(((const float*)fc2_b_raw)[i]));
        }
        const float* F2 = (const float*)fc2_w_raw;
        for (int i = gtid; i < (kR*kD)/2; i += gstride){
            int k = i >> 6, jp = i & 63;
            unsigned lo = f2bf(F2[(size_t)(2*jp  )*kR + k]);
            unsigned hi = f2bf(F2[(size_t)(2*jp+1)*kR + k]);
            stg32((unsigned*)fc2T + (size_t)k*64 + jp, lo | (hi<<16));
        }
    } else {
        for (int i = gtid; i < 3*kR; i += gstride) {
            stg32((unsigned*)&bias[i],        __float_as_uint(bf2f(((const u16*)b_ih_raw)[i])));
            stg32((unsigned*)&bias[3*kR + i], __float_as_uint(bf2f(((const u16*)b_hh_raw)[i])));
        }
        for (int i = gtid; i < kD; i += gstride) {
            stg32((unsigned*)&bias[6*kR + i],      __float_as_uint(bf2f(((const u16*)fc1_b_raw)[i])));
            stg32((unsigned*)&bias[6*kR + kD + i], __float_as_uint(bf2f(((const u16*)fc2_b_raw)[i])));
        }
        const u16* F2 = (const u16*)fc2_w_raw;
        for (int i = gtid; i < (kR*kD)/2; i += gstride){
            int k = i >> 6, jp = i & 63;
            unsigned lo = F2[(size_t)(2*jp  )*kR + k];
            unsigned hi = F2[(size_t)(2*jp+1)*kR + k];
            stg32((unsigned*)fc2T + (size_t)k*64 + jp, lo | (hi<<16));
        }
    }
    for (int i = gtid; i < (int)((kB*kR)/2); i += gstride) stg32((unsigned*)h_b16 + i, 0u);
    gbar(flags, 1, 0, 4);                // tok 1: global barrier

    const u16* ENCX = F32 ? cv_encx : (const u16*)enc_in_raw;
    const u16* WF1  = F32 ? cv_fc1  : (const u16*)fc1_w_raw;

    // ---- wM via MFMA, block-local (r9) ----
    bf16x8 wM[3][8];
    {
        u16* sA2 = smem;                 // 48 x 136  (13056 B)
        u16* sM  = smem + 6528;          // 16 x 2064 (66048 B)
        for (int q = tid; q < 48*16; q += kNT){
            int r = q >> 4, c = q & 15;
            int g = r >> 4, rr2 = r & 15;
            size_t off = (size_t)(g*kR + wgc*16 + rr2)*kD + c*8;
            bf16x8 v;
            if (F32) v = pack8(*(const float4*)((const float*)w_ih_raw + off),
                               *(const float4*)((const float*)w_ih_raw + off + 4));
            else     v = *(const bf16x8*)((const u16*)w_ih_raw + off);
            *(bf16x8*)&sA2[r*136 + c*8] = v;
        }
        __syncthreads();
        const f32x4 zzm = {0.f,0.f,0.f,0.f};
        for (int g=0; g<3; ++g){
            __syncthreads();
            for (int jc=0; jc<4; ++jc){
                f32x4 acc[4] = {zzm,zzm,zzm,zzm};
#pragma unroll
                for (int jt=0; jt<4; ++jt){
                    const int cb = wv*256 + (jc*4+jt)*16;
#pragma unroll
                    for (int kk=0; kk<4; ++kk){
                        bf16x8 a = *(const bf16x8*)&sA2[(g*16+ar)*136 + kk*32 + aq*8];
                        bf16x8 b = *(const bf16x8*)(fc2T + (size_t)(cb + ar)*kD + kk*32 + aq*8);
                        acc[jt] = __builtin_amdgcn_mfma_f32_16x16x32_bf16(a, b, acc[jt],0,0,0);
                    }
                }
#pragma unroll
                for (int jt=0; jt<4; ++jt){
                    const int cb = wv*256 + (jc*4+jt)*16;
#pragma unroll
                    for (int rr2=0; rr2<4; ++rr2)
                        sM[(aq*4+rr2)*2064 + cb + ar] = f2bf(acc[jt][rr2]);
                }
            }
            __syncthreads();
#pragma unroll
            for (int c=0; c<8; ++c)
                wM[g][c] = *(const bf16x8*)&sM[ar*2064 + 256*wv + 32*c + aq*8];
        }
        __syncthreads();
    }

    // ---- per-thread constants ----
    float4 b4;
    {
        const int hc = wgc*16 + ar;
        b4.x = aldf(&bias[hc])      + aldf(&bias[3*kR+hc]);
        b4.y = aldf(&bias[kR+hc])   + aldf(&bias[4*kR+hc]);
        b4.z = aldf(&bias[2*kR+hc]);
        b4.w = aldf(&bias[5*kR+hc]);
    }
    float hprev[4] = {0.f, 0.f, 0.f, 0.f};

    // ---- fc1 ----
    if (wgc < kSin) {
        const int g = wv>>2, mt = wv&3;
        const f32x4 zz = {0.f,0.f,0.f,0.f};
        f32x4 ae[4] = {zz,zz,zz,zz};
        small_gemm<8,4>(ENCX + ((size_t)mrow0*kSin + wgc)*kD, kSin*kD, WF1, kD, ae, smem);
#pragma unroll
        for (int jt=0; jt<8; ++jt){
            if ((jt&1) != g) continue;
            int col = jt*16 + ar;
            float fb = aldf(&bias[6*kR + col]);
#pragma unroll
            for (int rr=0; rr<4; ++rr){
                int m = mrow0 + mt*16 + aq*4 + rr;
                float v = ae[jt>>1][rr] + fb;
                u16 hb = f2bf(v);
                unsigned other = (unsigned)__shfl_xor((int)(unsigned)hb, 1);
                if (!(ar&1))
                    stg32((unsigned*)(enc_act + ((size_t)wgc*kB + m)*kD + col),
                          (unsigned)hb | (other<<16));
                if (wgc == kSin-1)
                    stg32((unsigned*)(encF + (size_t)m*kD + col), __float_as_uint(v));
            }
        }
    }
    gbar(flags, 2, dom, 2);              // tok 2: half-domain barrier

    // ---- encoder: 49 GRU steps; token H_t = t+3 ----
    for (int t = 0; t < kSin-1; ++t) {
        gru_phase_enc(h_b16 + (size_t)(t & 7)*HS, h_b16 + (size_t)((t+1) & 7)*HS,
                      enc_act + (size_t)t*kB*kD, wB, wI, b4, hprev, wgc, mrow0, smem,
                      flags, (t==0 ? 0 : t+2), dom, (t > 0) && ((t & 7) == 0), t+3);
    }

    // ---- decoder prologue: v0 = W_ih*encF, c3 = W_ih*fc2_b (f32, L2-hot) ----
    float v3[3][4] = {{0,0,0,0},{0,0,0,0},{0,0,0,0}};
    float c3[3] = {0.f,0.f,0.f};
    if (tid < 256){
        const int mtp = tid>>6, aqp = (tid&63)>>4, arp = tid&15;
        const int hc = wgc*16 + arp;
#pragma unroll
        for (int g=0; g<3; ++g){
            float cacc = 0.f, va0=0.f, va1=0.f, va2=0.f, va3=0.f;
            const int m0 = mrow0 + mtp*16 + aqp*4;
            if (F32){
                const float* wr = (const float*)w_ih_raw + (size_t)(g*kR + hc)*kD;
                for (int j=0;j<kD;++j){
                    float wj = wr[j];
                    cacc += wj * bias[6*kR + kD + j];
                    va0 += wj * encF[(size_t)(m0+0)*kD + j];
                    va1 += wj * encF[(size_t)(m0+1)*kD + j];
                    va2 += wj * encF[(size_t)(m0+2)*kD + j];
                    va3 += wj * encF[(size_t)(m0+3)*kD + j];
                }
            } else {
                const u16* wr = (const u16*)w_ih_raw + (size_t)(g*kR + hc)*kD;
                for (int j=0;j<kD;++j){
                    float wj = bf2f(wr[j]);
                    cacc += wj * bias[6*kR + kD + j];
                    va0 += wj * encF[(size_t)(m0+0)*kD + j];
                    va1 += wj * encF[(size_t)(m0+1)*kD + j];
                    va2 += wj * encF[(size_t)(m0+2)*kD + j];
                    va3 += wj * encF[(size_t)(m0+3)*kD + j];
                }
            }
            c3[g] = cacc;
            v3[g][0]=va0; v3[g][1]=va1; v3[g][2]=va2; v3[g][3]=va3;
        }
    }

    // ---- decoder: 25 uniform GRU steps; token = 52+d ----
    for (int d = 0; d < kT; ++d) {
        const int g = 49 + d;
        gru_phase_dec(h_b16 + (size_t)(g & 7)*HS, h_b16 + (size_t)((g+1) & 7)*HS,
                      hist + (size_t)d*HS,
                      wB, wM, b4, c3, v3, hprev, wgc, mrow0, smem,
                      flags, 51+d, 52+d, dom, (g & 7) == 0, d > 0);
    }
    gbar(flags, 77, 0, 4);               // full barrier: all hist visible

    // ---- F-pass via MFMA: F = hist @ fc2_w^T, hist in slice-major ----
    {
        const u16* FC2W = F32 ? cv_fc2 : (const u16*)fc2_w_raw;
        for (int u = wg; u < (kT*kB)/16; u += kNB){
            const int e = u >> 3, r0 = (u & 7) << 4;
            const u16* hb  = hist + (size_t)e*HS;
            const u16* wb2 = FC2W + (size_t)(wv*16 + ar)*kR;
            const f32x4 zzf = {0.f,0.f,0.f,0.f};
            f32x4 acc = zzf;
            for (int kk=0; kk<64; ++kk){
                const int s = 2*kk + (aq>>1);
                bf16x8 a = *(const bf16x8*)(hb + (((s*128 + r0 + ar)<<4) + (aq&1)*8));
                bf16x8 b = *(const bf16x8*)(wb2 + kk*32 + aq*8);
                acc = __builtin_amdgcn_mfma_f32_16x16x32_bf16(a, b, acc,0,0,0);
            }
#pragma unroll
            for (int rr2=0; rr2<4; ++rr2)
                stg32((unsigned*)&Fbuf[(size_t)(e*kB + r0 + aq*4 + rr2)*kD + wv*16 + ar],
                      __float_as_uint(acc[rr2]));
        }
    }
    gbar(flags, 78, 0, 4);               // full barrier: F visible

    // ---- prefix pass: out[m][e][j] = encF[m][j] + sum_{q<=e}(F_q + fc2_b) ----
    if (wg < 32){
        const int id = wg*kNT + tid;
        const int m = id >> 7, j = id & 127;
        float acc = encF[(size_t)m*kD + j];
        const float fb = bias[6*kR + kD + j];
        for (int e=0; e<kT; ++e){
            acc += Fbuf[(size_t)(e*kB + m)*kD + j] + fb;
            const size_t ob = ((size_t)m*kT + e)*kD + j;
            if (F32) ((float*)out_raw)[ob] = acc;
            else     ((u16*)out_raw)[ob]   = f2bf(acc);
        }
    }
}

// ---------------- host launcher ----------------
extern "C" void kernel_launch(void* const* d_in, const int* in_sizes, int n_in,
                              void* d_out, int out_size, void* d_ws, size_t ws_size,
                              hipStream_t stream)
{
    size_t off = 0;
    char* ws = (char*)d_ws;
    auto alloc = [&](size_t bytes) -> char* {
        char* p = ws + off;
        off = (off + bytes + 255) & ~(size_t)255;
        return p;
    };
    u16*   enc_act = (u16*)alloc((size_t)kSin*kB*kD*2);
    u16*   h_b16   = (u16*)alloc((size_t)kRing*kB*kR*2);         // 4 MB ring
    u16*   hist    = (u16*)alloc((size_t)kT*kB*kR*2);            // 12.8 MB slice-major
    float* Fbuf    = (float*)alloc((size_t)kT*kB*kD*4);          // 1.6 MB
    u16*   fc2T    = (u16*)alloc((size_t)kR*kD*2);               // 512 KB
    float* encF    = (float*)alloc((size_t)kB*kD*4);
    float* bias    = (float*)alloc((size_t)(6*kR + 2*kD)*4);
    int*   flags   = (int*)alloc((size_t)kNB*16*4);
    u16*   cv_encx = (u16*)alloc((size_t)kB*kSin*kD*2);
    u16*   cv_fc2  = (u16*)alloc((size_t)kD*kR*2);
    u16*   cv_fc1  = (u16*)alloc((size_t)kD*kD*2);
    (void)ws_size; (void)in_sizes; (void)n_in; (void)out_size;

    seq2seq_kernel<<<dim3(kNB), dim3(kNT), 0, stream>>>(
        d_in[0], d_in[2], d_in[3], d_in[4], d_in[5], d_in[6], d_in[7], d_in[8], d_in[9],
        d_out,
        enc_act, h_b16, hist, Fbuf, fc2T, encF, bias, flags,
        cv_encx, cv_fc2, cv_fc1);
}